// Round 1
// 1487.898 us; speedup vs baseline: 2.2562x; 2.2562x over previous
//
#include <hip/hip_runtime.h>
#include <math.h>

// Problem constants
#define B_    8192
#define DIN_  1024
#define HID_  2048
#define LAT_  256
#define KC_   4096   // codebook size

using bfrag8 = __attribute__((ext_vector_type(8))) short;   // 8 bf16 (4 VGPR)
using short8 = __attribute__((ext_vector_type(8))) short;
using half8  = __attribute__((ext_vector_type(8))) _Float16;
using facc4  = __attribute__((ext_vector_type(4))) float;   // MFMA C/D frag

__device__ __forceinline__ unsigned short f2bf(float f) {
    union { float f; unsigned int u; } c; c.f = f;
    unsigned int u = c.u;
    return (unsigned short)((u + 0x7FFFu + ((u >> 16) & 1u)) >> 16);   // RNE
}

__device__ __forceinline__ unsigned short f2h_bits(float f) {
    union { _Float16 h; unsigned short u; } c; c.h = (_Float16)f;
    return c.u;
}

// ---------------------------------------------------------------------------
// Encoder GEMM via fp16-split MFMA (Ozaki-style, 2 components, 3 classes).
//   A   = Ahi + Alo/4096                 (f16 splits of fp32 activations)
//   W64 = WThi + WTlo/4096  (= W*64)     (f16 splits of fp32 weights * 64)
//   C   = (sum AhiWhi)/64 + (sum AhiWlo + AloWhi)/(64*4096) + bias
// accA (hi*hi) is promoted into fp32 master every 256 k (blocked accumulation:
// in-block fp32 error ~1e-7; master adds ~z*1.7e-7) -> z_e error ~2.5e-7,
// ~4x the fp64 path's 6e-8 and well under the ~1e-6 ref-deviation that passes.
// Tile: 128x64 block, 4 waves (2x2), wave tile 64x32 (4x2 frags of 16x16x32).
// LDS XOR-swizzled (granule ^= row&7): conflict-free b128 reads+writes.
// ---------------------------------------------------------------------------
template <int GELU, int OUT_SPLIT>
__global__ __launch_bounds__(256, 2) void gemm_split_f16(
    const unsigned short* __restrict__ Ahi, const unsigned short* __restrict__ Alo,
    const unsigned short* __restrict__ WThi, const unsigned short* __restrict__ WTlo,
    const float* __restrict__ bias,
    unsigned short* __restrict__ Chi, unsigned short* __restrict__ Clo,
    float* __restrict__ Cf32,
    int M, int N, int K)
{
    __shared__ __align__(16) unsigned short AsH[128 * 64];   // 16 KB
    __shared__ __align__(16) unsigned short AsL[128 * 64];   // 16 KB
    __shared__ __align__(16) unsigned short WsH[64 * 64];    // 8 KB
    __shared__ __align__(16) unsigned short WsL[64 * 64];    // 8 KB

    const int tid  = threadIdx.x;
    const int wave = tid >> 6;
    const int lane = tid & 63;
    const int wm   = wave & 1;        // wave row (2x2 wave grid)
    const int wn   = wave >> 1;       // wave col
    const int quad = lane >> 4;
    const int ln   = lane & 15;
    const int n0 = blockIdx.x * 64;   // x = n-tile: consecutive blocks share A tile (L2)
    const int m0 = blockIdx.y * 128;

    const facc4 fz4 = {0.0f, 0.0f, 0.0f, 0.0f};
    facc4 accA[4][2] = {};    // hi*hi, scale 64, reset every 256 k
    facc4 accB[4][2] = {};    // hi*lo + lo*hi, scale 64*4096, full-K chain
    facc4 master[4][2] = {};  // blocked sum of accA

    for (int k0 = 0; k0 < K; k0 += 64) {
        // stage A tiles: 128 rows x 8 granules(16B) per comp -> 4 iters
#pragma unroll
        for (int i = 0; i < 4; ++i) {
            const int idx = i * 256 + tid;
            const int row = idx >> 3;
            const int g   = idx & 7;
            const int dst = row * 64 + ((g ^ (row & 7)) << 3);
            const size_t src = (size_t)(m0 + row) * K + k0 + g * 8;
            *reinterpret_cast<short8*>(&AsH[dst]) =
                *reinterpret_cast<const short8*>(&Ahi[src]);
            *reinterpret_cast<short8*>(&AsL[dst]) =
                *reinterpret_cast<const short8*>(&Alo[src]);
        }
        // stage W tiles: 64 rows x 8 granules per comp -> 2 iters
#pragma unroll
        for (int i = 0; i < 2; ++i) {
            const int idx = i * 256 + tid;
            const int row = idx >> 3;
            const int g   = idx & 7;
            const int dst = row * 64 + ((g ^ (row & 7)) << 3);
            const size_t src = (size_t)(n0 + row) * K + k0 + g * 8;
            *reinterpret_cast<short8*>(&WsH[dst]) =
                *reinterpret_cast<const short8*>(&WThi[src]);
            *reinterpret_cast<short8*>(&WsL[dst]) =
                *reinterpret_cast<const short8*>(&WTlo[src]);
        }
        __syncthreads();
#pragma unroll
        for (int ks = 0; ks < 64; ks += 32) {
            const int gq = (ks >> 3) + quad;      // source granule for this chunk
            half8 aH[4], aL[4], bH[2], bL[2];
#pragma unroll
            for (int f = 0; f < 4; ++f) {
                const int row = wm * 64 + f * 16 + ln;
                const int off = row * 64 + ((gq ^ (ln & 7)) << 3);
                aH[f] = *reinterpret_cast<const half8*>(&AsH[off]);
                aL[f] = *reinterpret_cast<const half8*>(&AsL[off]);
            }
#pragma unroll
            for (int f = 0; f < 2; ++f) {
                const int row = wn * 32 + f * 16 + ln;
                const int off = row * 64 + ((gq ^ (ln & 7)) << 3);
                bH[f] = *reinterpret_cast<const half8*>(&WsH[off]);
                bL[f] = *reinterpret_cast<const half8*>(&WsL[off]);
            }
#pragma unroll
            for (int fm = 0; fm < 4; ++fm)
#pragma unroll
                for (int fn = 0; fn < 2; ++fn)
                    accA[fm][fn] = __builtin_amdgcn_mfma_f32_16x16x32_f16(
                        aH[fm], bH[fn], accA[fm][fn], 0, 0, 0);
#pragma unroll
            for (int fm = 0; fm < 4; ++fm)
#pragma unroll
                for (int fn = 0; fn < 2; ++fn)
                    accB[fm][fn] = __builtin_amdgcn_mfma_f32_16x16x32_f16(
                        aH[fm], bL[fn], accB[fm][fn], 0, 0, 0);
#pragma unroll
            for (int fm = 0; fm < 4; ++fm)
#pragma unroll
                for (int fn = 0; fn < 2; ++fn)
                    accB[fm][fn] = __builtin_amdgcn_mfma_f32_16x16x32_f16(
                        aL[fm], bH[fn], accB[fm][fn], 0, 0, 0);
        }
        __syncthreads();
        if ((k0 & 192) == 192) {            // end of each 256-k block: promote
#pragma unroll
            for (int fm = 0; fm < 4; ++fm)
#pragma unroll
                for (int fn = 0; fn < 2; ++fn) {
                    master[fm][fn] += accA[fm][fn];
                    accA[fm][fn] = fz4;
                }
        }
    }

    const double SC_HI = 0.015625;               // 1/64
    const double SC_LO = 3.814697265625e-06;     // 1/(64*4096)
#pragma unroll
    for (int fn = 0; fn < 2; ++fn) {
        const int col = n0 + wn * 32 + fn * 16 + ln;
        const double bb = (double)bias[col];
#pragma unroll
        for (int fm = 0; fm < 4; ++fm) {
            const int rbase = m0 + wm * 64 + fm * 16 + quad * 4;
#pragma unroll
            for (int r = 0; r < 4; ++r) {
                double v = (double)master[fm][fn][r] * SC_HI
                         + (double)accB[fm][fn][r] * SC_LO + bb;
                if (GELU) v = 0.5 * v * (1.0 + erf(v * 0.70710678118654752440));
                if (OUT_SPLIT) {
                    const float hf = (float)v;
                    const _Float16 hi = (_Float16)hf;
                    const float lo = ((float)hf - (float)hi) * 4096.0f;
                    union { _Float16 h; unsigned short u; } c1, c2;
                    c1.h = hi; c2.h = (_Float16)lo;
                    Chi[(size_t)(rbase + r) * N + col] = c1.u;
                    Clo[(size_t)(rbase + r) * N + col] = c2.u;
                } else {
                    Cf32[(size_t)(rbase + r) * N + col] = (float)v;
                }
            }
        }
    }
}

// ---------------------------------------------------------------------------
// Split fp32 -> (hi, lo*4096) fp16 pair, elementwise (for x).
// ---------------------------------------------------------------------------
__global__ __launch_bounds__(256) void split_f32_f16x2(
    const float* __restrict__ X, unsigned short* __restrict__ Xhi,
    unsigned short* __restrict__ Xlo, int n4)
{
    const int i = blockIdx.x * 256 + threadIdx.x;
    if (i >= n4) return;
    const float4 v = reinterpret_cast<const float4*>(X)[i];
    ushort4 h, l;
    {
        _Float16 a = (_Float16)v.x; h.x = f2h_bits((float)a); l.x = f2h_bits((v.x - (float)a) * 4096.0f);
    }
    {
        _Float16 a = (_Float16)v.y; h.y = f2h_bits((float)a); l.y = f2h_bits((v.y - (float)a) * 4096.0f);
    }
    {
        _Float16 a = (_Float16)v.z; h.z = f2h_bits((float)a); l.z = f2h_bits((v.z - (float)a) * 4096.0f);
    }
    {
        _Float16 a = (_Float16)v.w; h.w = f2h_bits((float)a); l.w = f2h_bits((v.w - (float)a) * 4096.0f);
    }
    reinterpret_cast<ushort4*>(Xhi)[i] = h;
    reinterpret_cast<ushort4*>(Xlo)[i] = l;
}

// ---------------------------------------------------------------------------
// Weight prep: W [K,N] fp32 -> WThi/WTlo [N,K] f16 of (W*64, residual*4096).
// *64 is exact (power of 2); keeps w_lo in fp16 normal range.
// ---------------------------------------------------------------------------
__global__ __launch_bounds__(256) void wsplit_transpose(
    const float* __restrict__ W, unsigned short* __restrict__ WThi,
    unsigned short* __restrict__ WTlo, int K, int N)
{
    __shared__ float t[32][33];
    const int k0 = blockIdx.x * 32;
    const int n0 = blockIdx.y * 32;
    const int x = threadIdx.x;
    const int y = threadIdx.y;
#pragma unroll
    for (int i = 0; i < 4; ++i)
        t[y + i * 8][x] = W[(size_t)(k0 + y + i * 8) * N + n0 + x];
    __syncthreads();
#pragma unroll
    for (int i = 0; i < 4; ++i) {
        const float w = t[x][y + i * 8] * 64.0f;
        const _Float16 hi = (_Float16)w;
        const float lo = (w - (float)hi) * 4096.0f;
        WThi[(size_t)(n0 + y + i * 8) * K + k0 + x] = f2h_bits((float)hi);
        WTlo[(size_t)(n0 + y + i * 8) * K + k0 + x] = f2h_bits(lo);
    }
}

// ---------------------------------------------------------------------------
// Decoder GEMM: bf16 MFMA 16x16x32, 128x128 block tile, 4 waves (2x2 of 64x64)
// (unchanged — numerically free vs threshold)
// ---------------------------------------------------------------------------
template <int OUT_BF16>
__global__ __launch_bounds__(256) void gemm_mfma_bf16(
    const unsigned short* __restrict__ A,
    const unsigned short* __restrict__ WT,
    const float* __restrict__ bias,
    void* __restrict__ Cout,
    int M, int N, int K)
{
    __shared__ unsigned short As[128 * 64];   // [m][k], 64-k stage, 16 KB
    __shared__ unsigned short Bs[128 * 64];   // [n][k], 16 KB

    const int tid  = threadIdx.x;
    const int wave = tid >> 6;
    const int lane = tid & 63;
    const int wm   = wave & 1;
    const int wn   = wave >> 1;
    const int quad = lane >> 4;
    const int ln   = lane & 15;
    const int m0 = blockIdx.x * 128;
    const int n0 = blockIdx.y * 128;

    facc4 acc[4][4] = {};

    for (int k0 = 0; k0 < K; k0 += 64) {
#pragma unroll
        for (int i = 0; i < 4; ++i) {
            const int idx = i * 256 + tid;
            const int row = idx >> 3;
            const int c8  = (idx & 7) * 8;
            *reinterpret_cast<bfrag8*>(&As[row * 64 + c8]) =
                *reinterpret_cast<const bfrag8*>(&A[(size_t)(m0 + row) * K + k0 + c8]);
            *reinterpret_cast<bfrag8*>(&Bs[row * 64 + c8]) =
                *reinterpret_cast<const bfrag8*>(&WT[(size_t)(n0 + row) * K + k0 + c8]);
        }
        __syncthreads();
#pragma unroll
        for (int ks = 0; ks < 64; ks += 32) {
            bfrag8 am[4], bn[4];
#pragma unroll
            for (int f = 0; f < 4; ++f) {
                am[f] = *reinterpret_cast<const bfrag8*>(
                    &As[(wm * 64 + f * 16 + ln) * 64 + ks + quad * 8]);
                bn[f] = *reinterpret_cast<const bfrag8*>(
                    &Bs[(wn * 64 + f * 16 + ln) * 64 + ks + quad * 8]);
            }
#pragma unroll
            for (int fm = 0; fm < 4; ++fm)
#pragma unroll
                for (int fn = 0; fn < 4; ++fn)
                    acc[fm][fn] = __builtin_amdgcn_mfma_f32_16x16x32_bf16(
                        am[fm], bn[fn], acc[fm][fn], 0, 0, 0);
        }
        __syncthreads();
    }

#pragma unroll
    for (int fn = 0; fn < 4; ++fn) {
        const int col = n0 + wn * 64 + fn * 16 + ln;
        const float bf = bias[col];
#pragma unroll
        for (int fm = 0; fm < 4; ++fm) {
            const int rbase = m0 + wm * 64 + fm * 16 + quad * 4;
#pragma unroll
            for (int r = 0; r < 4; ++r) {
                float v = acc[fm][fn][r] + bf;
                if (OUT_BF16) {
                    v = 0.5f * v * (1.0f + erff(v * 0.70710678118654752440f));
                    ((unsigned short*)Cout)[(size_t)(rbase + r) * N + col] = f2bf(v);
                } else {
                    ((float*)Cout)[(size_t)(rbase + r) * N + col] = v;
                }
            }
        }
    }
}

// ---------------------------------------------------------------------------
// Cast+transpose weights: W [K,N] fp32 -> WT [N,K] bf16 (decoder, unchanged)
// ---------------------------------------------------------------------------
__global__ __launch_bounds__(256) void cast_transpose_w(
    const float* __restrict__ W, unsigned short* __restrict__ WT, int K, int N)
{
    __shared__ float t[32][33];
    const int k0 = blockIdx.x * 32;
    const int n0 = blockIdx.y * 32;
    const int x = threadIdx.x;
    const int y = threadIdx.y;
#pragma unroll
    for (int i = 0; i < 4; ++i)
        t[y + i * 8][x] = W[(size_t)(k0 + y + i * 8) * N + n0 + x];
    __syncthreads();
#pragma unroll
    for (int i = 0; i < 4; ++i)
        WT[(size_t)(n0 + y + i * 8) * K + k0 + x] = f2bf(t[x][y + i * 8]);
}

// ---------------------------------------------------------------------------
// Transpose embed [4096,256] -> embedT [256,4096] (fp32, for vq_argmin)
// ---------------------------------------------------------------------------
__global__ __launch_bounds__(256) void transpose_embed(
    const float* __restrict__ E, float* __restrict__ ET)
{
    __shared__ float t[32][33];
    const int c0 = blockIdx.x * 32;
    const int l0 = blockIdx.y * 32;
    const int x = threadIdx.x;
    const int y = threadIdx.y;
#pragma unroll
    for (int i = 0; i < 4; ++i)
        t[y + i * 8][x] = E[(size_t)(c0 + y + i * 8) * LAT_ + l0 + x];
    __syncthreads();
#pragma unroll
    for (int i = 0; i < 4; ++i)
        ET[(size_t)(l0 + y + i * 8) * KC_ + c0 + x] = t[x][y + i * 8];
}

// ---------------------------------------------------------------------------
// rowsq[r] = fp32( fp64 sum of X[r,:].^2 ), rows of width LAT_=256.
// ---------------------------------------------------------------------------
__global__ __launch_bounds__(64) void rowsq_kernel(
    const float* __restrict__ X, float* __restrict__ out,
    float* __restrict__ loss_slot)
{
    const int r = blockIdx.x;
    const float4 v = reinterpret_cast<const float4*>(X + (size_t)r * LAT_)[threadIdx.x];
    double s = (double)v.x * v.x + (double)v.y * v.y + (double)v.z * v.z + (double)v.w * v.w;
#pragma unroll
    for (int off = 32; off; off >>= 1) s += __shfl_down(s, off, 64);
    if (threadIdx.x == 0) {
        out[r] = (float)s;
        if (loss_slot != nullptr && r == 0) *loss_slot = 0.0f;
    }
}

// ---------------------------------------------------------------------------
// Fused distance + argmin (unchanged):
//   dist32 = fp32( fp32(zsq + esq) - fp32(2 * dot_f64) ), argmin first-index.
// ---------------------------------------------------------------------------
__global__ __launch_bounds__(256) void vq_argmin(
    const float* __restrict__ Z,     // [B,256]
    const float* __restrict__ ET,    // [256,4096]
    const float* __restrict__ esq,   // [4096] fp32
    const float* __restrict__ zsq,   // [B]    fp32
    float* __restrict__ pval, int* __restrict__ pidx)  // [B,8]
{
    __shared__ float Zs[16][68];
    __shared__ float Es[16][64];
    __shared__ float rv[64][16];
    __shared__ int   ri[64][16];

    const int tid = threadIdx.x;
    const int tx = tid & 15;
    const int ty = tid >> 4;
    const int m0 = blockIdx.x * 64;
    const int split = blockIdx.y;
    const int nbeg = split * (KC_ / 8);

    float zsqv[4];
#pragma unroll
    for (int i = 0; i < 4; ++i) zsqv[i] = zsq[m0 + ty * 4 + i];

    float bestv[4];
    int   besti[4];
#pragma unroll
    for (int i = 0; i < 4; ++i) { bestv[i] = 3.4e38f; besti[i] = 0; }

    for (int n0 = nbeg; n0 < nbeg + (KC_ / 8); n0 += 64) {
        double acc[4][4] = {};
        for (int k0 = 0; k0 < LAT_; k0 += 16) {
#pragma unroll
            for (int i = 0; i < 4; ++i) {
                int m = (tid >> 4) + i * 16;
                Zs[tid & 15][m] = Z[(size_t)(m0 + m) * LAT_ + k0 + (tid & 15)];
            }
#pragma unroll
            for (int i = 0; i < 4; ++i) {
                int k = (tid >> 6) + i * 4;
                Es[k][tid & 63] = ET[(size_t)(k0 + k) * KC_ + n0 + (tid & 63)];
            }
            __syncthreads();
#pragma unroll
            for (int kk = 0; kk < 16; ++kk) {
                const float4 a = *reinterpret_cast<const float4*>(&Zs[kk][ty * 4]);
                const float4 b = *reinterpret_cast<const float4*>(&Es[kk][tx * 4]);
                const double av[4] = {(double)a.x, (double)a.y, (double)a.z, (double)a.w};
                const double bv[4] = {(double)b.x, (double)b.y, (double)b.z, (double)b.w};
#pragma unroll
                for (int i = 0; i < 4; ++i)
#pragma unroll
                    for (int j = 0; j < 4; ++j)
                        acc[i][j] = fma(av[i], bv[j], acc[i][j]);
            }
            __syncthreads();
        }
#pragma unroll
        for (int j = 0; j < 4; ++j) {
            const int n = n0 + tx * 4 + j;
            const float es = esq[n];
#pragma unroll
            for (int i = 0; i < 4; ++i) {
                const float S   = zsqv[i] + es;
                const float t2m = (float)(2.0 * acc[i][j]);
                const float sc  = S - t2m;
                if (sc < bestv[i] || (sc == bestv[i] && n < besti[i])) {
                    bestv[i] = sc; besti[i] = n;
                }
            }
        }
    }
#pragma unroll
    for (int i = 0; i < 4; ++i) { rv[ty * 4 + i][tx] = bestv[i]; ri[ty * 4 + i][tx] = besti[i]; }
    __syncthreads();
    if (tid < 64) {
        float bv = rv[tid][0]; int bi = ri[tid][0];
#pragma unroll
        for (int t = 1; t < 16; ++t) {
            const float v = rv[tid][t]; const int ix = ri[tid][t];
            if (v < bv || (v == bv && ix < bi)) { bv = v; bi = ix; }
        }
        pval[(m0 + tid) * 8 + split] = bv;
        pidx[(m0 + tid) * 8 + split] = bi;
    }
}

// ---------------------------------------------------------------------------
// Finalize: reduce 8 partials -> index (float), gather z_q (bf16), loss atomics
// ---------------------------------------------------------------------------
__global__ __launch_bounds__(64) void vq_finalize(
    const float* __restrict__ pval, const int* __restrict__ pidx,
    const float* __restrict__ Z, const float* __restrict__ E,
    unsigned short* __restrict__ zqb, float* __restrict__ out_idx,
    float* __restrict__ loss_slot)
{
    const int row = blockIdx.x;
    __shared__ int sidx;
    if (threadIdx.x == 0) {
        float bv = pval[row * 8]; int bi = pidx[row * 8];
#pragma unroll
        for (int s = 1; s < 8; ++s) {
            const float v = pval[row * 8 + s]; const int ix = pidx[row * 8 + s];
            if (v < bv || (v == bv && ix < bi)) { bv = v; bi = ix; }
        }
        sidx = bi;
        out_idx[row] = (float)bi;
    }
    __syncthreads();
    const int idx = sidx;
    const float4 e = reinterpret_cast<const float4*>(E + (size_t)idx * LAT_)[threadIdx.x];
    const float4 z = reinterpret_cast<const float4*>(Z + (size_t)row * LAT_)[threadIdx.x];
    ushort4 q; q.x = f2bf(e.x); q.y = f2bf(e.y); q.z = f2bf(e.z); q.w = f2bf(e.w);
    reinterpret_cast<ushort4*>(zqb + (size_t)row * LAT_)[threadIdx.x] = q;
    const float dx = z.x - e.x, dy = z.y - e.y, dz = z.z - e.z, dw = z.w - e.w;
    float s = dx * dx + dy * dy + dz * dz + dw * dw;
#pragma unroll
    for (int off = 32; off; off >>= 1) s += __shfl_down(s, off, 64);
    if (threadIdx.x == 0)
        atomicAdd(loss_slot, s * (1.25f / ((float)B_ * (float)LAT_)));
}

// ---------------------------------------------------------------------------
extern "C" void kernel_launch(void* const* d_in, const int* in_sizes, int n_in,
                              void* d_out, int out_size, void* d_ws, size_t ws_size,
                              hipStream_t stream)
{
    const float* x   = (const float*)d_in[0];
    const float* W1  = (const float*)d_in[1];
    const float* b1  = (const float*)d_in[2];
    const float* W2  = (const float*)d_in[3];
    const float* b2  = (const float*)d_in[4];
    const float* W3  = (const float*)d_in[5];
    const float* b3  = (const float*)d_in[6];
    const float* emb = (const float*)d_in[7];
    const float* D1  = (const float*)d_in[8];
    const float* d1  = (const float*)d_in[9];
    const float* D2  = (const float*)d_in[10];
    const float* d2  = (const float*)d_in[11];
    const float* D3  = (const float*)d_in[12];
    const float* d3  = (const float*)d_in[13];
    float* out = (float*)d_out;

    // Workspace map (peak 153 MB < proven 156 MB). 1 MB = 1<<20. Overlays:
    //  [  0, 32M)  h1hi      -> embT [0,4M) after enc2 -> g1b after vq
    //  [ 32, 64M)  h1lo      -> zqb [32,36M) after enc2 -> g2b after dec1
    //  [ 64, 96M)  xhi[64,80) xlo[80,96) -> h2hi (enc2) -> wt1/wt2/wt3 after enc3
    //  [ 96,128M)  h2lo
    //  [128,136M)  ze fp32
    //  [136,152M)  enc weight splits: W1T{hi,lo} -> W2T{hi,lo} -> W3T{hi,lo}
    //  [152,153M)  esq, zsq, pval, pidx
    char* ws = (char*)d_ws;
    const size_t MB = 1u << 20;
    unsigned short* h1hi = (unsigned short*)(ws);
    unsigned short* h1lo = (unsigned short*)(ws + 32 * MB);
    float*          embT = (float*)(ws);                    // after enc2
    unsigned short* g1b  = (unsigned short*)(ws);           // after vq
    unsigned short* zqb  = (unsigned short*)(ws + 32 * MB); // after enc2
    unsigned short* g2b  = (unsigned short*)(ws + 32 * MB); // after dec1
    unsigned short* xhi  = (unsigned short*)(ws + 64 * MB);
    unsigned short* xlo  = (unsigned short*)(ws + 80 * MB);
    unsigned short* h2hi = (unsigned short*)(ws + 64 * MB); // after enc1
    unsigned short* h2lo = (unsigned short*)(ws + 96 * MB);
    unsigned short* wt1  = (unsigned short*)(ws + 64 * MB); // after enc3
    unsigned short* wt2  = (unsigned short*)(ws + 65 * MB);
    unsigned short* wt3  = (unsigned short*)(ws + 73 * MB);
    float* ze = (float*)(ws + 128 * MB);
    unsigned short* w1thi = (unsigned short*)(ws + 136 * MB);
    unsigned short* w1tlo = (unsigned short*)(ws + 140 * MB);
    unsigned short* w2thi = (unsigned short*)(ws + 136 * MB); // after enc1
    unsigned short* w2tlo = (unsigned short*)(ws + 144 * MB);
    unsigned short* w3thi = (unsigned short*)(ws + 136 * MB); // after enc2
    unsigned short* w3tlo = (unsigned short*)(ws + 137 * MB);
    float* esq  = (float*)(ws + 152 * MB);
    float* zsq  = (float*)(ws + 152 * MB + 64 * 1024);
    float* pval = (float*)(ws + 152 * MB + 128 * 1024);
    int*   pidx = (int*)  (ws + 152 * MB + 384 * 1024);

    float* loss_slot = out + (size_t)B_ * DIN_;     // d_out[8388608]
    float* out_idx   = loss_slot + 1;               // d_out[8388609..]

    // codebook prep (esq kernel also zeroes loss slot)
    rowsq_kernel<<<KC_, 64, 0, stream>>>(emb, esq, loss_slot);

    // input + first-layer weight splits
    split_f32_f16x2<<<(B_ * DIN_ / 4 + 255) / 256, 256, 0, stream>>>(x, xhi, xlo, B_ * DIN_ / 4);
    wsplit_transpose<<<dim3(DIN_ / 32, HID_ / 32), dim3(32, 8), 0, stream>>>(W1, w1thi, w1tlo, DIN_, HID_);

    // enc1: x -> h1 (split output)
    gemm_split_f16<1, 1><<<dim3(HID_ / 64, B_ / 128), 256, 0, stream>>>(
        xhi, xlo, w1thi, w1tlo, b1, h1hi, h1lo, nullptr, B_, HID_, DIN_);

    // W2 split (overlays W1T; after enc1)
    wsplit_transpose<<<dim3(HID_ / 32, HID_ / 32), dim3(32, 8), 0, stream>>>(W2, w2thi, w2tlo, HID_, HID_);

    // enc2: h1 -> h2 (xsplit dead, h2hi overlays it)
    gemm_split_f16<1, 1><<<dim3(HID_ / 64, B_ / 128), 256, 0, stream>>>(
        h1hi, h1lo, w2thi, w2tlo, b2, h2hi, h2lo, nullptr, B_, HID_, HID_);

    // h1 region dead: embT. W3 split overlays W2T region.
    transpose_embed<<<dim3(KC_ / 32, LAT_ / 32), dim3(32, 8), 0, stream>>>(emb, embT);
    wsplit_transpose<<<dim3(HID_ / 32, LAT_ / 32), dim3(32, 8), 0, stream>>>(W3, w3thi, w3tlo, HID_, LAT_);

    // enc3: h2 -> ze (fp32 out, no gelu)
    gemm_split_f16<0, 0><<<dim3(LAT_ / 64, B_ / 128), 256, 0, stream>>>(
        h2hi, h2lo, w3thi, w3tlo, b3, nullptr, nullptr, ze, B_, LAT_, HID_);

    // z row norms
    rowsq_kernel<<<B_, 64, 0, stream>>>(ze, zsq, nullptr);

    // decoder weight prep (h2 dead after enc3; wt* overlay it)
    cast_transpose_w<<<dim3(LAT_ / 32, HID_ / 32), dim3(32, 8), 0, stream>>>(D1, wt1, LAT_, HID_);
    cast_transpose_w<<<dim3(HID_ / 32, HID_ / 32), dim3(32, 8), 0, stream>>>(D2, wt2, HID_, HID_);
    cast_transpose_w<<<dim3(HID_ / 32, DIN_ / 32), dim3(32, 8), 0, stream>>>(D3, wt3, HID_, DIN_);

    // VQ — numpy-fp32-mimicking scores, first-index tie-break (unchanged)
    vq_argmin<<<dim3(B_ / 64, 8), 256, 0, stream>>>(ze, embT, esq, zsq, pval, pidx);
    vq_finalize<<<B_, 64, 0, stream>>>(pval, pidx, ze, emb, zqb, out_idx, loss_slot);

    // decoder — bf16 MFMA (unchanged)
    gemm_mfma_bf16<1><<<dim3(B_ / 128, HID_ / 128), 256, 0, stream>>>(zqb, wt1, d1, (void*)g1b, B_, HID_, LAT_);
    gemm_mfma_bf16<1><<<dim3(B_ / 128, HID_ / 128), 256, 0, stream>>>(g1b, wt2, d2, (void*)g2b, B_, HID_, HID_);
    gemm_mfma_bf16<0><<<dim3(B_ / 128, DIN_ / 128), 256, 0, stream>>>(g2b, wt3, d3, (void*)out, B_, DIN_, HID_);
}

// Round 2
// 1145.723 us; speedup vs baseline: 2.9300x; 1.2987x over previous
//
#include <hip/hip_runtime.h>
#include <math.h>

// Problem constants
#define B_    8192
#define DIN_  1024
#define HID_  2048
#define LAT_  256
#define KC_   4096   // codebook size

using bfrag8 = __attribute__((ext_vector_type(8))) short;   // 8 bf16 (4 VGPR)
using short8 = __attribute__((ext_vector_type(8))) short;
using half8  = __attribute__((ext_vector_type(8))) _Float16;
using facc4  = __attribute__((ext_vector_type(4))) float;   // MFMA C/D frag

__device__ __forceinline__ unsigned short f2bf(float f) {
    union { float f; unsigned int u; } c; c.f = f;
    unsigned int u = c.u;
    return (unsigned short)((u + 0x7FFFu + ((u >> 16) & 1u)) >> 16);   // RNE
}

__device__ __forceinline__ unsigned short f2h_bits(float f) {
    union { _Float16 h; unsigned short u; } c; c.h = (_Float16)f;
    return c.u;
}

// ---------------------------------------------------------------------------
// Encoder GEMM via fp16-split MFMA (Ozaki-style, 2 components, 3 classes).
// (unchanged from round 1 — verified passing)
// ---------------------------------------------------------------------------
template <int GELU, int OUT_SPLIT>
__global__ __launch_bounds__(256, 2) void gemm_split_f16(
    const unsigned short* __restrict__ Ahi, const unsigned short* __restrict__ Alo,
    const unsigned short* __restrict__ WThi, const unsigned short* __restrict__ WTlo,
    const float* __restrict__ bias,
    unsigned short* __restrict__ Chi, unsigned short* __restrict__ Clo,
    float* __restrict__ Cf32,
    int M, int N, int K)
{
    __shared__ __align__(16) unsigned short AsH[128 * 64];   // 16 KB
    __shared__ __align__(16) unsigned short AsL[128 * 64];   // 16 KB
    __shared__ __align__(16) unsigned short WsH[64 * 64];    // 8 KB
    __shared__ __align__(16) unsigned short WsL[64 * 64];    // 8 KB

    const int tid  = threadIdx.x;
    const int wave = tid >> 6;
    const int lane = tid & 63;
    const int wm   = wave & 1;        // wave row (2x2 wave grid)
    const int wn   = wave >> 1;       // wave col
    const int quad = lane >> 4;
    const int ln   = lane & 15;
    const int n0 = blockIdx.x * 64;   // x = n-tile: consecutive blocks share A tile (L2)
    const int m0 = blockIdx.y * 128;

    const facc4 fz4 = {0.0f, 0.0f, 0.0f, 0.0f};
    facc4 accA[4][2] = {};    // hi*hi, scale 64, reset every 256 k
    facc4 accB[4][2] = {};    // hi*lo + lo*hi, scale 64*4096, full-K chain
    facc4 master[4][2] = {};  // blocked sum of accA

    for (int k0 = 0; k0 < K; k0 += 64) {
        // stage A tiles: 128 rows x 8 granules(16B) per comp -> 4 iters
#pragma unroll
        for (int i = 0; i < 4; ++i) {
            const int idx = i * 256 + tid;
            const int row = idx >> 3;
            const int g   = idx & 7;
            const int dst = row * 64 + ((g ^ (row & 7)) << 3);
            const size_t src = (size_t)(m0 + row) * K + k0 + g * 8;
            *reinterpret_cast<short8*>(&AsH[dst]) =
                *reinterpret_cast<const short8*>(&Ahi[src]);
            *reinterpret_cast<short8*>(&AsL[dst]) =
                *reinterpret_cast<const short8*>(&Alo[src]);
        }
        // stage W tiles: 64 rows x 8 granules per comp -> 2 iters
#pragma unroll
        for (int i = 0; i < 2; ++i) {
            const int idx = i * 256 + tid;
            const int row = idx >> 3;
            const int g   = idx & 7;
            const int dst = row * 64 + ((g ^ (row & 7)) << 3);
            const size_t src = (size_t)(n0 + row) * K + k0 + g * 8;
            *reinterpret_cast<short8*>(&WsH[dst]) =
                *reinterpret_cast<const short8*>(&WThi[src]);
            *reinterpret_cast<short8*>(&WsL[dst]) =
                *reinterpret_cast<const short8*>(&WTlo[src]);
        }
        __syncthreads();
#pragma unroll
        for (int ks = 0; ks < 64; ks += 32) {
            const int gq = (ks >> 3) + quad;      // source granule for this chunk
            half8 aH[4], aL[4], bH[2], bL[2];
#pragma unroll
            for (int f = 0; f < 4; ++f) {
                const int row = wm * 64 + f * 16 + ln;
                const int off = row * 64 + ((gq ^ (ln & 7)) << 3);
                aH[f] = *reinterpret_cast<const half8*>(&AsH[off]);
                aL[f] = *reinterpret_cast<const half8*>(&AsL[off]);
            }
#pragma unroll
            for (int f = 0; f < 2; ++f) {
                const int row = wn * 32 + f * 16 + ln;
                const int off = row * 64 + ((gq ^ (ln & 7)) << 3);
                bH[f] = *reinterpret_cast<const half8*>(&WsH[off]);
                bL[f] = *reinterpret_cast<const half8*>(&WsL[off]);
            }
#pragma unroll
            for (int fm = 0; fm < 4; ++fm)
#pragma unroll
                for (int fn = 0; fn < 2; ++fn)
                    accA[fm][fn] = __builtin_amdgcn_mfma_f32_16x16x32_f16(
                        aH[fm], bH[fn], accA[fm][fn], 0, 0, 0);
#pragma unroll
            for (int fm = 0; fm < 4; ++fm)
#pragma unroll
                for (int fn = 0; fn < 2; ++fn)
                    accB[fm][fn] = __builtin_amdgcn_mfma_f32_16x16x32_f16(
                        aH[fm], bL[fn], accB[fm][fn], 0, 0, 0);
#pragma unroll
            for (int fm = 0; fm < 4; ++fm)
#pragma unroll
                for (int fn = 0; fn < 2; ++fn)
                    accB[fm][fn] = __builtin_amdgcn_mfma_f32_16x16x32_f16(
                        aL[fm], bH[fn], accB[fm][fn], 0, 0, 0);
        }
        __syncthreads();
        if ((k0 & 192) == 192) {            // end of each 256-k block: promote
#pragma unroll
            for (int fm = 0; fm < 4; ++fm)
#pragma unroll
                for (int fn = 0; fn < 2; ++fn) {
                    master[fm][fn] += accA[fm][fn];
                    accA[fm][fn] = fz4;
                }
        }
    }

    const double SC_HI = 0.015625;               // 1/64
    const double SC_LO = 3.814697265625e-06;     // 1/(64*4096)
#pragma unroll
    for (int fn = 0; fn < 2; ++fn) {
        const int col = n0 + wn * 32 + fn * 16 + ln;
        const double bb = (double)bias[col];
#pragma unroll
        for (int fm = 0; fm < 4; ++fm) {
            const int rbase = m0 + wm * 64 + fm * 16 + quad * 4;
#pragma unroll
            for (int r = 0; r < 4; ++r) {
                double v = (double)master[fm][fn][r] * SC_HI
                         + (double)accB[fm][fn][r] * SC_LO + bb;
                if (GELU) v = 0.5 * v * (1.0 + erf(v * 0.70710678118654752440));
                if (OUT_SPLIT) {
                    const float hf = (float)v;
                    const _Float16 hi = (_Float16)hf;
                    const float lo = ((float)hf - (float)hi) * 4096.0f;
                    union { _Float16 h; unsigned short u; } c1, c2;
                    c1.h = hi; c2.h = (_Float16)lo;
                    Chi[(size_t)(rbase + r) * N + col] = c1.u;
                    Clo[(size_t)(rbase + r) * N + col] = c2.u;
                } else {
                    Cf32[(size_t)(rbase + r) * N + col] = (float)v;
                }
            }
        }
    }
}

// ---------------------------------------------------------------------------
// Split fp32 -> (hi, lo*4096) fp16 pair, with pre-scale: v' = v*scale.
// scale must be a power of two (exact). Used for x (1.0), ze (1.0),
// embed (65536.0 — keeps e*2^16 in fp16 normal range, MFMA-denormal-safe).
// ---------------------------------------------------------------------------
__global__ __launch_bounds__(256) void split_scaled_f16x2(
    const float* __restrict__ X, unsigned short* __restrict__ Xhi,
    unsigned short* __restrict__ Xlo, int n4, float scale)
{
    const int i = blockIdx.x * 256 + threadIdx.x;
    if (i >= n4) return;
    const float4 v = reinterpret_cast<const float4*>(X)[i];
    ushort4 h, l;
    {
        const float s = v.x * scale;
        _Float16 a = (_Float16)s; h.x = f2h_bits((float)a); l.x = f2h_bits((s - (float)a) * 4096.0f);
    }
    {
        const float s = v.y * scale;
        _Float16 a = (_Float16)s; h.y = f2h_bits((float)a); l.y = f2h_bits((s - (float)a) * 4096.0f);
    }
    {
        const float s = v.z * scale;
        _Float16 a = (_Float16)s; h.z = f2h_bits((float)a); l.z = f2h_bits((s - (float)a) * 4096.0f);
    }
    {
        const float s = v.w * scale;
        _Float16 a = (_Float16)s; h.w = f2h_bits((float)a); l.w = f2h_bits((s - (float)a) * 4096.0f);
    }
    reinterpret_cast<ushort4*>(Xhi)[i] = h;
    reinterpret_cast<ushort4*>(Xlo)[i] = l;
}

// ---------------------------------------------------------------------------
// Weight prep: W [K,N] fp32 -> WThi/WTlo [N,K] f16 of (W*64, residual*4096).
// ---------------------------------------------------------------------------
__global__ __launch_bounds__(256) void wsplit_transpose(
    const float* __restrict__ W, unsigned short* __restrict__ WThi,
    unsigned short* __restrict__ WTlo, int K, int N)
{
    __shared__ float t[32][33];
    const int k0 = blockIdx.x * 32;
    const int n0 = blockIdx.y * 32;
    const int x = threadIdx.x;
    const int y = threadIdx.y;
#pragma unroll
    for (int i = 0; i < 4; ++i)
        t[y + i * 8][x] = W[(size_t)(k0 + y + i * 8) * N + n0 + x];
    __syncthreads();
#pragma unroll
    for (int i = 0; i < 4; ++i) {
        const float w = t[x][y + i * 8] * 64.0f;
        const _Float16 hi = (_Float16)w;
        const float lo = (w - (float)hi) * 4096.0f;
        WThi[(size_t)(n0 + y + i * 8) * K + k0 + x] = f2h_bits((float)hi);
        WTlo[(size_t)(n0 + y + i * 8) * K + k0 + x] = f2h_bits(lo);
    }
}

// ---------------------------------------------------------------------------
// VQ distance + argmin via fp16-split MFMA.
//   dot = accA*2^-16 + accB*2^-28 (combined in fp64, rounded to fp32 once —
//   mimics the proven fp32(2*dot_f64) semantics; added error ~1e-9 abs,
//   ~20x below the already-tolerated ~2e-8 z_e-induced dot deviation).
//   sc = fp32( fp32(zsq+esq) - fp32(2*dot) ), argmin first-index.
// Block: 128 rows x 512 entries (8 n-tiles of 64), grid (B/128, 8).
// Same 2x2-wave / XOR-swizzle template as gemm_split_f16.
// ---------------------------------------------------------------------------
__global__ __launch_bounds__(256, 2) void vq_argmin_mfma(
    const unsigned short* __restrict__ Zhi, const unsigned short* __restrict__ Zlo,
    const unsigned short* __restrict__ Ehi, const unsigned short* __restrict__ Elo,
    const float* __restrict__ esq, const float* __restrict__ zsq,
    float* __restrict__ pval, int* __restrict__ pidx)
{
    __shared__ __align__(16) unsigned short ZsH[128 * 64];   // 16 KB
    __shared__ __align__(16) unsigned short ZsL[128 * 64];   // 16 KB
    __shared__ __align__(16) unsigned short EsH[64 * 64];    // 8 KB
    __shared__ __align__(16) unsigned short EsL[64 * 64];    // 8 KB
    __shared__ float rbv[128][2];
    __shared__ int   rbi[128][2];

    const int tid  = threadIdx.x;
    const int wave = tid >> 6;
    const int lane = tid & 63;
    const int wm   = wave & 1;        // wave row (2x2 wave grid)
    const int wn   = wave >> 1;       // wave col
    const int quad = lane >> 4;
    const int ln   = lane & 15;
    const int m0    = blockIdx.x * 128;
    const int split = blockIdx.y;

    const double SC_A = 1.52587890625e-05;        // 2^-16
    const double SC_B = 3.725290298461914e-09;    // 2^-28

    float bestv[4][4];
    int   besti[4][4];
#pragma unroll
    for (int a = 0; a < 4; ++a)
#pragma unroll
        for (int b = 0; b < 4; ++b) { bestv[a][b] = 3.4e38f; besti[a][b] = 0; }

    for (int nt = 0; nt < 8; ++nt) {
        const int n0 = split * 512 + nt * 64;
        facc4 accA[4][2] = {};
        facc4 accB[4][2] = {};
        for (int k0 = 0; k0 < 256; k0 += 64) {
            __syncthreads();   // previous phase's LDS readers done
            // stage Z tile 128x64 (hi+lo)
#pragma unroll
            for (int i = 0; i < 4; ++i) {
                const int idx = i * 256 + tid;
                const int row = idx >> 3;
                const int g   = idx & 7;
                const int dst = row * 64 + ((g ^ (row & 7)) << 3);
                const size_t src = (size_t)(m0 + row) * LAT_ + k0 + g * 8;
                *reinterpret_cast<short8*>(&ZsH[dst]) =
                    *reinterpret_cast<const short8*>(&Zhi[src]);
                *reinterpret_cast<short8*>(&ZsL[dst]) =
                    *reinterpret_cast<const short8*>(&Zlo[src]);
            }
            // stage E tile 64x64 (hi+lo)
#pragma unroll
            for (int i = 0; i < 2; ++i) {
                const int idx = i * 256 + tid;
                const int row = idx >> 3;
                const int g   = idx & 7;
                const int dst = row * 64 + ((g ^ (row & 7)) << 3);
                const size_t src = (size_t)(n0 + row) * LAT_ + k0 + g * 8;
                *reinterpret_cast<short8*>(&EsH[dst]) =
                    *reinterpret_cast<const short8*>(&Ehi[src]);
                *reinterpret_cast<short8*>(&EsL[dst]) =
                    *reinterpret_cast<const short8*>(&Elo[src]);
            }
            __syncthreads();
#pragma unroll
            for (int ks = 0; ks < 64; ks += 32) {
                const int gq = (ks >> 3) + quad;
                half8 aH[4], aL[4], bH[2], bL[2];
#pragma unroll
                for (int f = 0; f < 4; ++f) {
                    const int row = wm * 64 + f * 16 + ln;
                    const int off = row * 64 + ((gq ^ (ln & 7)) << 3);
                    aH[f] = *reinterpret_cast<const half8*>(&ZsH[off]);
                    aL[f] = *reinterpret_cast<const half8*>(&ZsL[off]);
                }
#pragma unroll
                for (int f = 0; f < 2; ++f) {
                    const int row = wn * 32 + f * 16 + ln;
                    const int off = row * 64 + ((gq ^ (ln & 7)) << 3);
                    bH[f] = *reinterpret_cast<const half8*>(&EsH[off]);
                    bL[f] = *reinterpret_cast<const half8*>(&EsL[off]);
                }
#pragma unroll
                for (int fm = 0; fm < 4; ++fm)
#pragma unroll
                    for (int fn = 0; fn < 2; ++fn)
                        accA[fm][fn] = __builtin_amdgcn_mfma_f32_16x16x32_f16(
                            aH[fm], bH[fn], accA[fm][fn], 0, 0, 0);
#pragma unroll
                for (int fm = 0; fm < 4; ++fm)
#pragma unroll
                    for (int fn = 0; fn < 2; ++fn)
                        accB[fm][fn] = __builtin_amdgcn_mfma_f32_16x16x32_f16(
                            aH[fm], bL[fn], accB[fm][fn], 0, 0, 0);
#pragma unroll
                for (int fm = 0; fm < 4; ++fm)
#pragma unroll
                    for (int fn = 0; fn < 2; ++fn)
                        accB[fm][fn] = __builtin_amdgcn_mfma_f32_16x16x32_f16(
                            aL[fm], bH[fn], accB[fm][fn], 0, 0, 0);
            }
        }
        // n-tile epilogue: score + per-row argmin over this tile's 32 entries
        // (per wave), butterfly across the 16 frag columns, merge running best.
#pragma unroll
        for (int fm = 0; fm < 4; ++fm) {
            const float4 zq4 = *reinterpret_cast<const float4*>(
                &zsq[m0 + wm * 64 + fm * 16 + quad * 4]);
#pragma unroll
            for (int r = 0; r < 4; ++r) {
                float v0 = 3.4e38f; int i0 = 0;
#pragma unroll
                for (int fn = 0; fn < 2; ++fn) {
                    const int n = n0 + wn * 32 + fn * 16 + ln;
                    const float es = esq[n];
                    const float S = ((const float*)&zq4)[r] + es;
                    const double d = (double)accA[fm][fn][r] * SC_A
                                   + (double)accB[fm][fn][r] * SC_B;
                    const float t2m = (float)(2.0 * d);
                    const float sc = S - t2m;
                    if (sc < v0 || (sc == v0 && n < i0)) { v0 = sc; i0 = n; }
                }
#pragma unroll
                for (int mask = 1; mask < 16; mask <<= 1) {
                    const float v2 = __shfl_xor(v0, mask, 64);
                    const int   i2 = __shfl_xor(i0, mask, 64);
                    if (v2 < v0 || (v2 == v0 && i2 < i0)) { v0 = v2; i0 = i2; }
                }
                if (v0 < bestv[fm][r] || (v0 == bestv[fm][r] && i0 < besti[fm][r])) {
                    bestv[fm][r] = v0; besti[fm][r] = i0;
                }
            }
        }
    }

    if (ln == 0) {
#pragma unroll
        for (int fm = 0; fm < 4; ++fm)
#pragma unroll
            for (int r = 0; r < 4; ++r) {
                const int rl = wm * 64 + fm * 16 + quad * 4 + r;
                rbv[rl][wn] = bestv[fm][r];
                rbi[rl][wn] = besti[fm][r];
            }
    }
    __syncthreads();
    if (tid < 128) {
        float bv = rbv[tid][0]; int bi = rbi[tid][0];
        const float v = rbv[tid][1]; const int ix = rbi[tid][1];
        if (v < bv || (v == bv && ix < bi)) { bv = v; bi = ix; }
        pval[(size_t)(m0 + tid) * 8 + split] = bv;
        pidx[(m0 + tid) * 8 + split] = bi;
    }
}

// ---------------------------------------------------------------------------
// Decoder GEMM: bf16 MFMA 16x16x32 (unchanged — numerically free vs threshold)
// ---------------------------------------------------------------------------
template <int OUT_BF16>
__global__ __launch_bounds__(256) void gemm_mfma_bf16(
    const unsigned short* __restrict__ A,
    const unsigned short* __restrict__ WT,
    const float* __restrict__ bias,
    void* __restrict__ Cout,
    int M, int N, int K)
{
    __shared__ unsigned short As[128 * 64];   // [m][k], 64-k stage, 16 KB
    __shared__ unsigned short Bs[128 * 64];   // [n][k], 16 KB

    const int tid  = threadIdx.x;
    const int wave = tid >> 6;
    const int lane = tid & 63;
    const int wm   = wave & 1;
    const int wn   = wave >> 1;
    const int quad = lane >> 4;
    const int ln   = lane & 15;
    const int m0 = blockIdx.x * 128;
    const int n0 = blockIdx.y * 128;

    facc4 acc[4][4] = {};

    for (int k0 = 0; k0 < K; k0 += 64) {
#pragma unroll
        for (int i = 0; i < 4; ++i) {
            const int idx = i * 256 + tid;
            const int row = idx >> 3;
            const int c8  = (idx & 7) * 8;
            *reinterpret_cast<bfrag8*>(&As[row * 64 + c8]) =
                *reinterpret_cast<const bfrag8*>(&A[(size_t)(m0 + row) * K + k0 + c8]);
            *reinterpret_cast<bfrag8*>(&Bs[row * 64 + c8]) =
                *reinterpret_cast<const bfrag8*>(&WT[(size_t)(n0 + row) * K + k0 + c8]);
        }
        __syncthreads();
#pragma unroll
        for (int ks = 0; ks < 64; ks += 32) {
            bfrag8 am[4], bn[4];
#pragma unroll
            for (int f = 0; f < 4; ++f) {
                am[f] = *reinterpret_cast<const bfrag8*>(
                    &As[(wm * 64 + f * 16 + ln) * 64 + ks + quad * 8]);
                bn[f] = *reinterpret_cast<const bfrag8*>(
                    &Bs[(wn * 64 + f * 16 + ln) * 64 + ks + quad * 8]);
            }
#pragma unroll
            for (int fm = 0; fm < 4; ++fm)
#pragma unroll
                for (int fn = 0; fn < 4; ++fn)
                    acc[fm][fn] = __builtin_amdgcn_mfma_f32_16x16x32_bf16(
                        am[fm], bn[fn], acc[fm][fn], 0, 0, 0);
        }
        __syncthreads();
    }

#pragma unroll
    for (int fn = 0; fn < 4; ++fn) {
        const int col = n0 + wn * 64 + fn * 16 + ln;
        const float bf = bias[col];
#pragma unroll
        for (int fm = 0; fm < 4; ++fm) {
            const int rbase = m0 + wm * 64 + fm * 16 + quad * 4;
#pragma unroll
            for (int r = 0; r < 4; ++r) {
                float v = acc[fm][fn][r] + bf;
                if (OUT_BF16) {
                    v = 0.5f * v * (1.0f + erff(v * 0.70710678118654752440f));
                    ((unsigned short*)Cout)[(size_t)(rbase + r) * N + col] = f2bf(v);
                } else {
                    ((float*)Cout)[(size_t)(rbase + r) * N + col] = v;
                }
            }
        }
    }
}

// ---------------------------------------------------------------------------
// Cast+transpose weights: W [K,N] fp32 -> WT [N,K] bf16 (decoder, unchanged)
// ---------------------------------------------------------------------------
__global__ __launch_bounds__(256) void cast_transpose_w(
    const float* __restrict__ W, unsigned short* __restrict__ WT, int K, int N)
{
    __shared__ float t[32][33];
    const int k0 = blockIdx.x * 32;
    const int n0 = blockIdx.y * 32;
    const int x = threadIdx.x;
    const int y = threadIdx.y;
#pragma unroll
    for (int i = 0; i < 4; ++i)
        t[y + i * 8][x] = W[(size_t)(k0 + y + i * 8) * N + n0 + x];
    __syncthreads();
#pragma unroll
    for (int i = 0; i < 4; ++i)
        WT[(size_t)(n0 + y + i * 8) * K + k0 + x] = f2bf(t[x][y + i * 8]);
}

// ---------------------------------------------------------------------------
// rowsq[r] = fp32( fp64 sum of X[r,:].^2 ), rows of width LAT_=256.
// ---------------------------------------------------------------------------
__global__ __launch_bounds__(64) void rowsq_kernel(
    const float* __restrict__ X, float* __restrict__ out,
    float* __restrict__ loss_slot)
{
    const int r = blockIdx.x;
    const float4 v = reinterpret_cast<const float4*>(X + (size_t)r * LAT_)[threadIdx.x];
    double s = (double)v.x * v.x + (double)v.y * v.y + (double)v.z * v.z + (double)v.w * v.w;
#pragma unroll
    for (int off = 32; off; off >>= 1) s += __shfl_down(s, off, 64);
    if (threadIdx.x == 0) {
        out[r] = (float)s;
        if (loss_slot != nullptr && r == 0) *loss_slot = 0.0f;
    }
}

// ---------------------------------------------------------------------------
// Finalize: reduce 8 partials -> index (float), gather z_q (bf16), loss atomics
// ---------------------------------------------------------------------------
__global__ __launch_bounds__(64) void vq_finalize(
    const float* __restrict__ pval, const int* __restrict__ pidx,
    const float* __restrict__ Z, const float* __restrict__ E,
    unsigned short* __restrict__ zqb, float* __restrict__ out_idx,
    float* __restrict__ loss_slot)
{
    const int row = blockIdx.x;
    __shared__ int sidx;
    if (threadIdx.x == 0) {
        float bv = pval[row * 8]; int bi = pidx[row * 8];
#pragma unroll
        for (int s = 1; s < 8; ++s) {
            const float v = pval[row * 8 + s]; const int ix = pidx[row * 8 + s];
            if (v < bv || (v == bv && ix < bi)) { bv = v; bi = ix; }
        }
        sidx = bi;
        out_idx[row] = (float)bi;
    }
    __syncthreads();
    const int idx = sidx;
    const float4 e = reinterpret_cast<const float4*>(E + (size_t)idx * LAT_)[threadIdx.x];
    const float4 z = reinterpret_cast<const float4*>(Z + (size_t)row * LAT_)[threadIdx.x];
    ushort4 q; q.x = f2bf(e.x); q.y = f2bf(e.y); q.z = f2bf(e.z); q.w = f2bf(e.w);
    reinterpret_cast<ushort4*>(zqb + (size_t)row * LAT_)[threadIdx.x] = q;
    const float dx = z.x - e.x, dy = z.y - e.y, dz = z.z - e.z, dw = z.w - e.w;
    float s = dx * dx + dy * dy + dz * dz + dw * dw;
#pragma unroll
    for (int off = 32; off; off >>= 1) s += __shfl_down(s, off, 64);
    if (threadIdx.x == 0)
        atomicAdd(loss_slot, s * (1.25f / ((float)B_ * (float)LAT_)));
}

// ---------------------------------------------------------------------------
extern "C" void kernel_launch(void* const* d_in, const int* in_sizes, int n_in,
                              void* d_out, int out_size, void* d_ws, size_t ws_size,
                              hipStream_t stream)
{
    const float* x   = (const float*)d_in[0];
    const float* W1  = (const float*)d_in[1];
    const float* b1  = (const float*)d_in[2];
    const float* W2  = (const float*)d_in[3];
    const float* b2  = (const float*)d_in[4];
    const float* W3  = (const float*)d_in[5];
    const float* b3  = (const float*)d_in[6];
    const float* emb = (const float*)d_in[7];
    const float* D1  = (const float*)d_in[8];
    const float* d1  = (const float*)d_in[9];
    const float* D2  = (const float*)d_in[10];
    const float* d2  = (const float*)d_in[11];
    const float* D3  = (const float*)d_in[12];
    const float* d3  = (const float*)d_in[13];
    float* out = (float*)d_out;

    // Workspace map (peak 153 MB < proven 156 MB). 1 MB = 1<<20. Overlays:
    //  [  0, 32M)  h1hi  -> zehi [0,4M), zelo [4,8M) after enc3 -> g1b after vq
    //  [ 32, 64M)  h1lo  -> zqb [32,36M) after enc2 -> g2b after dec1
    //  [ 64, 96M)  xhi[64,80) xlo[80,96) -> h2hi (enc2) -> wt1/wt2/wt3 after enc3
    //  [ 96,128M)  h2lo
    //  [128,136M)  ze fp32
    //  [136,152M)  enc weight splits W1T/W2T/W3T; ehi[144,146) elo[146,148) after enc2
    //  [152,153M)  esq, zsq, pval, pidx
    char* ws = (char*)d_ws;
    const size_t MB = 1u << 20;
    unsigned short* h1hi = (unsigned short*)(ws);
    unsigned short* h1lo = (unsigned short*)(ws + 32 * MB);
    unsigned short* zehi = (unsigned short*)(ws);           // after enc3
    unsigned short* zelo = (unsigned short*)(ws + 4 * MB);  // after enc3
    unsigned short* g1b  = (unsigned short*)(ws);           // after vq
    unsigned short* zqb  = (unsigned short*)(ws + 32 * MB); // after enc2
    unsigned short* g2b  = (unsigned short*)(ws + 32 * MB); // after dec1
    unsigned short* xhi  = (unsigned short*)(ws + 64 * MB);
    unsigned short* xlo  = (unsigned short*)(ws + 80 * MB);
    unsigned short* h2hi = (unsigned short*)(ws + 64 * MB); // after enc1
    unsigned short* h2lo = (unsigned short*)(ws + 96 * MB);
    unsigned short* wt1  = (unsigned short*)(ws + 64 * MB); // after enc3
    unsigned short* wt2  = (unsigned short*)(ws + 65 * MB);
    unsigned short* wt3  = (unsigned short*)(ws + 73 * MB);
    float* ze = (float*)(ws + 128 * MB);
    unsigned short* w1thi = (unsigned short*)(ws + 136 * MB);
    unsigned short* w1tlo = (unsigned short*)(ws + 140 * MB);
    unsigned short* w2thi = (unsigned short*)(ws + 136 * MB); // after enc1
    unsigned short* w2tlo = (unsigned short*)(ws + 144 * MB);
    unsigned short* w3thi = (unsigned short*)(ws + 136 * MB); // after enc2
    unsigned short* w3tlo = (unsigned short*)(ws + 137 * MB);
    unsigned short* ehi   = (unsigned short*)(ws + 144 * MB); // after enc2 (w2tlo dead)
    unsigned short* elo   = (unsigned short*)(ws + 146 * MB);
    float* esq  = (float*)(ws + 152 * MB);
    float* zsq  = (float*)(ws + 152 * MB + 64 * 1024);
    float* pval = (float*)(ws + 152 * MB + 128 * 1024);
    int*   pidx = (int*)  (ws + 152 * MB + 384 * 1024);

    float* loss_slot = out + (size_t)B_ * DIN_;     // d_out[8388608]
    float* out_idx   = loss_slot + 1;               // d_out[8388609..]

    // codebook prep (esq kernel also zeroes loss slot)
    rowsq_kernel<<<KC_, 64, 0, stream>>>(emb, esq, loss_slot);

    // input + first-layer weight splits
    split_scaled_f16x2<<<(B_ * DIN_ / 4 + 255) / 256, 256, 0, stream>>>(
        x, xhi, xlo, B_ * DIN_ / 4, 1.0f);
    wsplit_transpose<<<dim3(DIN_ / 32, HID_ / 32), dim3(32, 8), 0, stream>>>(W1, w1thi, w1tlo, DIN_, HID_);

    // enc1: x -> h1 (split output)
    gemm_split_f16<1, 1><<<dim3(HID_ / 64, B_ / 128), 256, 0, stream>>>(
        xhi, xlo, w1thi, w1tlo, b1, h1hi, h1lo, nullptr, B_, HID_, DIN_);

    // W2 split (overlays W1T; after enc1)
    wsplit_transpose<<<dim3(HID_ / 32, HID_ / 32), dim3(32, 8), 0, stream>>>(W2, w2thi, w2tlo, HID_, HID_);

    // enc2: h1 -> h2 (xsplit dead, h2hi overlays it)
    gemm_split_f16<1, 1><<<dim3(HID_ / 64, B_ / 128), 256, 0, stream>>>(
        h1hi, h1lo, w2thi, w2tlo, b2, h2hi, h2lo, nullptr, B_, HID_, HID_);

    // codebook split (x2^16, over dead w2tlo region) + W3 split (after enc2)
    split_scaled_f16x2<<<(KC_ * LAT_ / 4 + 255) / 256, 256, 0, stream>>>(
        emb, ehi, elo, KC_ * LAT_ / 4, 65536.0f);
    wsplit_transpose<<<dim3(HID_ / 32, LAT_ / 32), dim3(32, 8), 0, stream>>>(W3, w3thi, w3tlo, HID_, LAT_);

    // enc3: h2 -> ze (fp32 out, no gelu)
    gemm_split_f16<0, 0><<<dim3(LAT_ / 64, B_ / 128), 256, 0, stream>>>(
        h2hi, h2lo, w3thi, w3tlo, b3, nullptr, nullptr, ze, B_, LAT_, HID_);

    // z splits (over dead h1hi region) + z row norms
    split_scaled_f16x2<<<(B_ * LAT_ / 4 + 255) / 256, 256, 0, stream>>>(
        ze, zehi, zelo, B_ * LAT_ / 4, 1.0f);
    rowsq_kernel<<<B_, 64, 0, stream>>>(ze, zsq, nullptr);

    // decoder weight prep (h2 dead after enc3; wt* overlay it)
    cast_transpose_w<<<dim3(LAT_ / 32, HID_ / 32), dim3(32, 8), 0, stream>>>(D1, wt1, LAT_, HID_);
    cast_transpose_w<<<dim3(HID_ / 32, HID_ / 32), dim3(32, 8), 0, stream>>>(D2, wt2, HID_, HID_);
    cast_transpose_w<<<dim3(HID_ / 32, DIN_ / 32), dim3(32, 8), 0, stream>>>(D3, wt3, HID_, DIN_);

    // VQ — MFMA split distances, numpy-fp32-mimicking scores, first-index ties
    vq_argmin_mfma<<<dim3(B_ / 128, 8), 256, 0, stream>>>(
        zehi, zelo, ehi, elo, esq, zsq, pval, pidx);
    vq_finalize<<<B_, 64, 0, stream>>>(pval, pidx, ze, emb, zqb, out_idx, loss_slot);

    // decoder — bf16 MFMA (unchanged)
    gemm_mfma_bf16<1><<<dim3(B_ / 128, HID_ / 128), 256, 0, stream>>>(zqb, wt1, d1, (void*)g1b, B_, HID_, LAT_);
    gemm_mfma_bf16<1><<<dim3(B_ / 128, HID_ / 128), 256, 0, stream>>>(g1b, wt2, d2, (void*)g2b, B_, HID_, HID_);
    gemm_mfma_bf16<0><<<dim3(B_ / 128, DIN_ / 128), 256, 0, stream>>>(g2b, wt3, d3, (void*)out, B_, DIN_, HID_);
}

// Round 3
// 1097.025 us; speedup vs baseline: 3.0601x; 1.0444x over previous
//
#include <hip/hip_runtime.h>
#include <math.h>

// Problem constants
#define B_    8192
#define DIN_  1024
#define HID_  2048
#define LAT_  256
#define KC_   4096   // codebook size

using bfrag8 = __attribute__((ext_vector_type(8))) short;   // 8 bf16 (4 VGPR)
using short8 = __attribute__((ext_vector_type(8))) short;
using half8  = __attribute__((ext_vector_type(8))) _Float16;
using facc4  = __attribute__((ext_vector_type(4))) float;   // MFMA C/D frag

__device__ __forceinline__ unsigned short f2bf(float f) {
    union { float f; unsigned int u; } c; c.f = f;
    unsigned int u = c.u;
    return (unsigned short)((u + 0x7FFFu + ((u >> 16) & 1u)) >> 16);   // RNE
}

__device__ __forceinline__ unsigned short f2h_bits(float f) {
    union { _Float16 h; unsigned short u; } c; c.h = (_Float16)f;
    return c.u;
}

// Async global->LDS, 16B per lane. LDS dest is wave-uniform base + lane*16.
__device__ __forceinline__ void gload16(const unsigned short* g, unsigned short* l) {
    __builtin_amdgcn_global_load_lds(
        (const __attribute__((address_space(1))) void*)(g),
        (__attribute__((address_space(3))) void*)(l), 16, 0, 0);
}

// ---------------------------------------------------------------------------
// Encoder GEMM via fp16-split MFMA (Ozaki-style, 2 components, 3 classes).
// Staging via global_load_lds: LDS dest linear in lane order; global source
// granule pre-swizzled g^(row&7) so LDS contents are BYTE-IDENTICAL to the
// verified XOR layout (read side unchanged -> bit-identical results).
// OUT_SPLIT: 0 = f32 only, 1 = f16 split only, 2 = f32 + f16 split.
// ---------------------------------------------------------------------------
template <int GELU, int OUT_SPLIT>
__global__ __launch_bounds__(256, 3) void gemm_split_f16(
    const unsigned short* __restrict__ Ahi, const unsigned short* __restrict__ Alo,
    const unsigned short* __restrict__ WThi, const unsigned short* __restrict__ WTlo,
    const float* __restrict__ bias,
    unsigned short* __restrict__ Chi, unsigned short* __restrict__ Clo,
    float* __restrict__ Cf32,
    int M, int N, int K)
{
    __shared__ __align__(16) unsigned short AsH[128 * 64];   // 16 KB
    __shared__ __align__(16) unsigned short AsL[128 * 64];   // 16 KB
    __shared__ __align__(16) unsigned short WsH[64 * 64];    // 8 KB
    __shared__ __align__(16) unsigned short WsL[64 * 64];    // 8 KB

    const int tid  = threadIdx.x;
    const int wave = tid >> 6;
    const int lane = tid & 63;
    const int wm   = wave & 1;        // wave row (2x2 wave grid)
    const int wn   = wave >> 1;       // wave col
    const int quad = lane >> 4;
    const int ln   = lane & 15;
    const int n0 = blockIdx.x * 64;   // x = n-tile: consecutive blocks share A tile (L2)
    const int m0 = blockIdx.y * 128;

    const facc4 fz4 = {0.0f, 0.0f, 0.0f, 0.0f};
    facc4 accA[4][2] = {};    // hi*hi, scale 64, reset every 256 k
    facc4 accB[4][2] = {};    // hi*lo + lo*hi, scale 64*4096, full-K chain
    facc4 master[4][2] = {};  // blocked sum of accA

    for (int k0 = 0; k0 < K; k0 += 64) {
        // stage A tiles 128x64 (hi+lo): dest linear, source granule-swizzled
#pragma unroll
        for (int i = 0; i < 4; ++i) {
            const int idx = i * 256 + tid;
            const int row = idx >> 3;
            const int gs  = (idx & 7) ^ (row & 7);
            const int wb  = i * 256 + (tid & 192);     // wave-uniform granule base
            const size_t src = (size_t)(m0 + row) * K + k0 + gs * 8;
            gload16(&Ahi[src], &AsH[wb * 8]);
            gload16(&Alo[src], &AsL[wb * 8]);
        }
        // stage W tiles 64x64 (hi+lo)
#pragma unroll
        for (int i = 0; i < 2; ++i) {
            const int idx = i * 256 + tid;
            const int row = idx >> 3;
            const int gs  = (idx & 7) ^ (row & 7);
            const int wb  = i * 256 + (tid & 192);
            const size_t src = (size_t)(n0 + row) * K + k0 + gs * 8;
            gload16(&WThi[src], &WsH[wb * 8]);
            gload16(&WTlo[src], &WsL[wb * 8]);
        }
        __syncthreads();
#pragma unroll
        for (int ks = 0; ks < 64; ks += 32) {
            const int gq = (ks >> 3) + quad;      // source granule for this chunk
            half8 aH[4], aL[4], bH[2], bL[2];
#pragma unroll
            for (int f = 0; f < 4; ++f) {
                const int row = wm * 64 + f * 16 + ln;
                const int off = row * 64 + ((gq ^ (ln & 7)) << 3);
                aH[f] = *reinterpret_cast<const half8*>(&AsH[off]);
                aL[f] = *reinterpret_cast<const half8*>(&AsL[off]);
            }
#pragma unroll
            for (int f = 0; f < 2; ++f) {
                const int row = wn * 32 + f * 16 + ln;
                const int off = row * 64 + ((gq ^ (ln & 7)) << 3);
                bH[f] = *reinterpret_cast<const half8*>(&WsH[off]);
                bL[f] = *reinterpret_cast<const half8*>(&WsL[off]);
            }
#pragma unroll
            for (int fm = 0; fm < 4; ++fm)
#pragma unroll
                for (int fn = 0; fn < 2; ++fn)
                    accA[fm][fn] = __builtin_amdgcn_mfma_f32_16x16x32_f16(
                        aH[fm], bH[fn], accA[fm][fn], 0, 0, 0);
#pragma unroll
            for (int fm = 0; fm < 4; ++fm)
#pragma unroll
                for (int fn = 0; fn < 2; ++fn)
                    accB[fm][fn] = __builtin_amdgcn_mfma_f32_16x16x32_f16(
                        aH[fm], bL[fn], accB[fm][fn], 0, 0, 0);
#pragma unroll
            for (int fm = 0; fm < 4; ++fm)
#pragma unroll
                for (int fn = 0; fn < 2; ++fn)
                    accB[fm][fn] = __builtin_amdgcn_mfma_f32_16x16x32_f16(
                        aL[fm], bH[fn], accB[fm][fn], 0, 0, 0);
        }
        __syncthreads();
        if ((k0 & 192) == 192) {            // end of each 256-k block: promote
#pragma unroll
            for (int fm = 0; fm < 4; ++fm)
#pragma unroll
                for (int fn = 0; fn < 2; ++fn) {
                    master[fm][fn] += accA[fm][fn];
                    accA[fm][fn] = fz4;
                }
        }
    }

    const double SC_HI = 0.015625;               // 1/64
    const double SC_LO = 3.814697265625e-06;     // 1/(64*4096)
#pragma unroll
    for (int fn = 0; fn < 2; ++fn) {
        const int col = n0 + wn * 32 + fn * 16 + ln;
        const double bb = (double)bias[col];
#pragma unroll
        for (int fm = 0; fm < 4; ++fm) {
            const int rbase = m0 + wm * 64 + fm * 16 + quad * 4;
#pragma unroll
            for (int r = 0; r < 4; ++r) {
                double v = (double)master[fm][fn][r] * SC_HI
                         + (double)accB[fm][fn][r] * SC_LO + bb;
                if (GELU) v = 0.5 * v * (1.0 + erf(v * 0.70710678118654752440));
                const float hf = (float)v;
                if (OUT_SPLIT == 1 || OUT_SPLIT == 2) {
                    const _Float16 hi = (_Float16)hf;
                    const float lo = (hf - (float)hi) * 4096.0f;
                    union { _Float16 h; unsigned short u; } c1, c2;
                    c1.h = hi; c2.h = (_Float16)lo;
                    Chi[(size_t)(rbase + r) * N + col] = c1.u;
                    Clo[(size_t)(rbase + r) * N + col] = c2.u;
                }
                if (OUT_SPLIT == 0 || OUT_SPLIT == 2) {
                    Cf32[(size_t)(rbase + r) * N + col] = hf;
                }
            }
        }
    }
}

// ---------------------------------------------------------------------------
// Split fp32 -> (hi, lo*4096) fp16 pair, with pre-scale: v' = v*scale.
// scale must be a power of two (exact). Used for x (1.0) and
// embed (65536.0 — keeps e*2^16 in fp16 normal range, MFMA-denormal-safe).
// ---------------------------------------------------------------------------
__global__ __launch_bounds__(256) void split_scaled_f16x2(
    const float* __restrict__ X, unsigned short* __restrict__ Xhi,
    unsigned short* __restrict__ Xlo, int n4, float scale)
{
    const int i = blockIdx.x * 256 + threadIdx.x;
    if (i >= n4) return;
    const float4 v = reinterpret_cast<const float4*>(X)[i];
    ushort4 h, l;
    {
        const float s = v.x * scale;
        _Float16 a = (_Float16)s; h.x = f2h_bits((float)a); l.x = f2h_bits((s - (float)a) * 4096.0f);
    }
    {
        const float s = v.y * scale;
        _Float16 a = (_Float16)s; h.y = f2h_bits((float)a); l.y = f2h_bits((s - (float)a) * 4096.0f);
    }
    {
        const float s = v.z * scale;
        _Float16 a = (_Float16)s; h.z = f2h_bits((float)a); l.z = f2h_bits((s - (float)a) * 4096.0f);
    }
    {
        const float s = v.w * scale;
        _Float16 a = (_Float16)s; h.w = f2h_bits((float)a); l.w = f2h_bits((s - (float)a) * 4096.0f);
    }
    reinterpret_cast<ushort4*>(Xhi)[i] = h;
    reinterpret_cast<ushort4*>(Xlo)[i] = l;
}

// ---------------------------------------------------------------------------
// Weight prep: W [K,N] fp32 -> WThi/WTlo [N,K] f16 of (W*64, residual*4096).
// ---------------------------------------------------------------------------
__global__ __launch_bounds__(256) void wsplit_transpose(
    const float* __restrict__ W, unsigned short* __restrict__ WThi,
    unsigned short* __restrict__ WTlo, int K, int N)
{
    __shared__ float t[32][33];
    const int k0 = blockIdx.x * 32;
    const int n0 = blockIdx.y * 32;
    const int x = threadIdx.x;
    const int y = threadIdx.y;
#pragma unroll
    for (int i = 0; i < 4; ++i)
        t[y + i * 8][x] = W[(size_t)(k0 + y + i * 8) * N + n0 + x];
    __syncthreads();
#pragma unroll
    for (int i = 0; i < 4; ++i) {
        const float w = t[x][y + i * 8] * 64.0f;
        const _Float16 hi = (_Float16)w;
        const float lo = (w - (float)hi) * 4096.0f;
        WThi[(size_t)(n0 + y + i * 8) * K + k0 + x] = f2h_bits((float)hi);
        WTlo[(size_t)(n0 + y + i * 8) * K + k0 + x] = f2h_bits(lo);
    }
}

// ---------------------------------------------------------------------------
// VQ distance + argmin via fp16-split MFMA (verified round 2).
// Staging switched to global_load_lds with pre-swizzled source (bit-identical
// LDS contents -> bit-identical scores/indices).
// ---------------------------------------------------------------------------
__global__ __launch_bounds__(256, 2) void vq_argmin_mfma(
    const unsigned short* __restrict__ Zhi, const unsigned short* __restrict__ Zlo,
    const unsigned short* __restrict__ Ehi, const unsigned short* __restrict__ Elo,
    const float* __restrict__ esq, const float* __restrict__ zsq,
    float* __restrict__ pval, int* __restrict__ pidx)
{
    __shared__ __align__(16) unsigned short ZsH[128 * 64];   // 16 KB
    __shared__ __align__(16) unsigned short ZsL[128 * 64];   // 16 KB
    __shared__ __align__(16) unsigned short EsH[64 * 64];    // 8 KB
    __shared__ __align__(16) unsigned short EsL[64 * 64];    // 8 KB
    __shared__ float rbv[128][2];
    __shared__ int   rbi[128][2];

    const int tid  = threadIdx.x;
    const int wave = tid >> 6;
    const int lane = tid & 63;
    const int wm   = wave & 1;        // wave row (2x2 wave grid)
    const int wn   = wave >> 1;       // wave col
    const int quad = lane >> 4;
    const int ln   = lane & 15;
    const int m0    = blockIdx.x * 128;
    const int split = blockIdx.y;

    const double SC_A = 1.52587890625e-05;        // 2^-16
    const double SC_B = 3.725290298461914e-09;    // 2^-28

    float bestv[4][4];
    int   besti[4][4];
#pragma unroll
    for (int a = 0; a < 4; ++a)
#pragma unroll
        for (int b = 0; b < 4; ++b) { bestv[a][b] = 3.4e38f; besti[a][b] = 0; }

    for (int nt = 0; nt < 8; ++nt) {
        const int n0 = split * 512 + nt * 64;
        facc4 accA[4][2] = {};
        facc4 accB[4][2] = {};
        for (int k0 = 0; k0 < 256; k0 += 64) {
            __syncthreads();   // previous phase's LDS readers done
            // stage Z tile 128x64 (hi+lo)
#pragma unroll
            for (int i = 0; i < 4; ++i) {
                const int idx = i * 256 + tid;
                const int row = idx >> 3;
                const int gs  = (idx & 7) ^ (row & 7);
                const int wb  = i * 256 + (tid & 192);
                const size_t src = (size_t)(m0 + row) * LAT_ + k0 + gs * 8;
                gload16(&Zhi[src], &ZsH[wb * 8]);
                gload16(&Zlo[src], &ZsL[wb * 8]);
            }
            // stage E tile 64x64 (hi+lo)
#pragma unroll
            for (int i = 0; i < 2; ++i) {
                const int idx = i * 256 + tid;
                const int row = idx >> 3;
                const int gs  = (idx & 7) ^ (row & 7);
                const int wb  = i * 256 + (tid & 192);
                const size_t src = (size_t)(n0 + row) * LAT_ + k0 + gs * 8;
                gload16(&Ehi[src], &EsH[wb * 8]);
                gload16(&Elo[src], &EsL[wb * 8]);
            }
            __syncthreads();
#pragma unroll
            for (int ks = 0; ks < 64; ks += 32) {
                const int gq = (ks >> 3) + quad;
                half8 aH[4], aL[4], bH[2], bL[2];
#pragma unroll
                for (int f = 0; f < 4; ++f) {
                    const int row = wm * 64 + f * 16 + ln;
                    const int off = row * 64 + ((gq ^ (ln & 7)) << 3);
                    aH[f] = *reinterpret_cast<const half8*>(&ZsH[off]);
                    aL[f] = *reinterpret_cast<const half8*>(&ZsL[off]);
                }
#pragma unroll
                for (int f = 0; f < 2; ++f) {
                    const int row = wn * 32 + f * 16 + ln;
                    const int off = row * 64 + ((gq ^ (ln & 7)) << 3);
                    bH[f] = *reinterpret_cast<const half8*>(&EsH[off]);
                    bL[f] = *reinterpret_cast<const half8*>(&EsL[off]);
                }
#pragma unroll
                for (int fm = 0; fm < 4; ++fm)
#pragma unroll
                    for (int fn = 0; fn < 2; ++fn)
                        accA[fm][fn] = __builtin_amdgcn_mfma_f32_16x16x32_f16(
                            aH[fm], bH[fn], accA[fm][fn], 0, 0, 0);
#pragma unroll
                for (int fm = 0; fm < 4; ++fm)
#pragma unroll
                    for (int fn = 0; fn < 2; ++fn)
                        accB[fm][fn] = __builtin_amdgcn_mfma_f32_16x16x32_f16(
                            aH[fm], bL[fn], accB[fm][fn], 0, 0, 0);
#pragma unroll
                for (int fm = 0; fm < 4; ++fm)
#pragma unroll
                    for (int fn = 0; fn < 2; ++fn)
                        accB[fm][fn] = __builtin_amdgcn_mfma_f32_16x16x32_f16(
                            aL[fm], bH[fn], accB[fm][fn], 0, 0, 0);
            }
        }
        // n-tile epilogue: score + per-row argmin over this tile's 32 entries
#pragma unroll
        for (int fm = 0; fm < 4; ++fm) {
            const float4 zq4 = *reinterpret_cast<const float4*>(
                &zsq[m0 + wm * 64 + fm * 16 + quad * 4]);
#pragma unroll
            for (int r = 0; r < 4; ++r) {
                float v0 = 3.4e38f; int i0 = 0;
#pragma unroll
                for (int fn = 0; fn < 2; ++fn) {
                    const int n = n0 + wn * 32 + fn * 16 + ln;
                    const float es = esq[n];
                    const float S = ((const float*)&zq4)[r] + es;
                    const double d = (double)accA[fm][fn][r] * SC_A
                                   + (double)accB[fm][fn][r] * SC_B;
                    const float t2m = (float)(2.0 * d);
                    const float sc = S - t2m;
                    if (sc < v0 || (sc == v0 && n < i0)) { v0 = sc; i0 = n; }
                }
#pragma unroll
                for (int mask = 1; mask < 16; mask <<= 1) {
                    const float v2 = __shfl_xor(v0, mask, 64);
                    const int   i2 = __shfl_xor(i0, mask, 64);
                    if (v2 < v0 || (v2 == v0 && i2 < i0)) { v0 = v2; i0 = i2; }
                }
                if (v0 < bestv[fm][r] || (v0 == bestv[fm][r] && i0 < besti[fm][r])) {
                    bestv[fm][r] = v0; besti[fm][r] = i0;
                }
            }
        }
    }

    if (ln == 0) {
#pragma unroll
        for (int fm = 0; fm < 4; ++fm)
#pragma unroll
            for (int r = 0; r < 4; ++r) {
                const int rl = wm * 64 + fm * 16 + quad * 4 + r;
                rbv[rl][wn] = bestv[fm][r];
                rbi[rl][wn] = besti[fm][r];
            }
    }
    __syncthreads();
    if (tid < 128) {
        float bv = rbv[tid][0]; int bi = rbi[tid][0];
        const float v = rbv[tid][1]; const int ix = rbi[tid][1];
        if (v < bv || (v == bv && ix < bi)) { bv = v; bi = ix; }
        pval[(size_t)(m0 + tid) * 8 + split] = bv;
        pidx[(m0 + tid) * 8 + split] = bi;
    }
}

// ---------------------------------------------------------------------------
// Decoder GEMM: bf16 MFMA 16x16x32 (staging via global_load_lds; LDS layout
// and numerics identical to verified version)
// ---------------------------------------------------------------------------
template <int OUT_BF16>
__global__ __launch_bounds__(256) void gemm_mfma_bf16(
    const unsigned short* __restrict__ A,
    const unsigned short* __restrict__ WT,
    const float* __restrict__ bias,
    void* __restrict__ Cout,
    int M, int N, int K)
{
    __shared__ __align__(16) unsigned short As[128 * 64];   // [m][k], 16 KB
    __shared__ __align__(16) unsigned short Bs[128 * 64];   // [n][k], 16 KB

    const int tid  = threadIdx.x;
    const int wave = tid >> 6;
    const int lane = tid & 63;
    const int wm   = wave & 1;
    const int wn   = wave >> 1;
    const int quad = lane >> 4;
    const int ln   = lane & 15;
    const int m0 = blockIdx.x * 128;
    const int n0 = blockIdx.y * 128;

    facc4 acc[4][4] = {};

    for (int k0 = 0; k0 < K; k0 += 64) {
#pragma unroll
        for (int i = 0; i < 4; ++i) {
            const int idx = i * 256 + tid;
            const int row = idx >> 3;
            const int c8  = (idx & 7) * 8;
            const int wb  = i * 256 + (tid & 192);
            gload16(&A[(size_t)(m0 + row) * K + k0 + c8], &As[wb * 8]);
            gload16(&WT[(size_t)(n0 + row) * K + k0 + c8], &Bs[wb * 8]);
        }
        __syncthreads();
#pragma unroll
        for (int ks = 0; ks < 64; ks += 32) {
            bfrag8 am[4], bn[4];
#pragma unroll
            for (int f = 0; f < 4; ++f) {
                am[f] = *reinterpret_cast<const bfrag8*>(
                    &As[(wm * 64 + f * 16 + ln) * 64 + ks + quad * 8]);
                bn[f] = *reinterpret_cast<const bfrag8*>(
                    &Bs[(wn * 64 + f * 16 + ln) * 64 + ks + quad * 8]);
            }
#pragma unroll
            for (int fm = 0; fm < 4; ++fm)
#pragma unroll
                for (int fn = 0; fn < 4; ++fn)
                    acc[fm][fn] = __builtin_amdgcn_mfma_f32_16x16x32_bf16(
                        am[fm], bn[fn], acc[fm][fn], 0, 0, 0);
        }
        __syncthreads();
    }

#pragma unroll
    for (int fn = 0; fn < 4; ++fn) {
        const int col = n0 + wn * 64 + fn * 16 + ln;
        const float bf = bias[col];
#pragma unroll
        for (int fm = 0; fm < 4; ++fm) {
            const int rbase = m0 + wm * 64 + fm * 16 + quad * 4;
#pragma unroll
            for (int r = 0; r < 4; ++r) {
                float v = acc[fm][fn][r] + bf;
                if (OUT_BF16) {
                    v = 0.5f * v * (1.0f + erff(v * 0.70710678118654752440f));
                    ((unsigned short*)Cout)[(size_t)(rbase + r) * N + col] = f2bf(v);
                } else {
                    ((float*)Cout)[(size_t)(rbase + r) * N + col] = v;
                }
            }
        }
    }
}

// ---------------------------------------------------------------------------
// Cast+transpose weights: W [K,N] fp32 -> WT [N,K] bf16 (decoder, unchanged)
// ---------------------------------------------------------------------------
__global__ __launch_bounds__(256) void cast_transpose_w(
    const float* __restrict__ W, unsigned short* __restrict__ WT, int K, int N)
{
    __shared__ float t[32][33];
    const int k0 = blockIdx.x * 32;
    const int n0 = blockIdx.y * 32;
    const int x = threadIdx.x;
    const int y = threadIdx.y;
#pragma unroll
    for (int i = 0; i < 4; ++i)
        t[y + i * 8][x] = W[(size_t)(k0 + y + i * 8) * N + n0 + x];
    __syncthreads();
#pragma unroll
    for (int i = 0; i < 4; ++i)
        WT[(size_t)(n0 + y + i * 8) * K + k0 + x] = f2bf(t[x][y + i * 8]);
}

// ---------------------------------------------------------------------------
// rowsq[r] = fp32( fp64 sum of X[r,:].^2 ), rows of width LAT_=256.
// ---------------------------------------------------------------------------
__global__ __launch_bounds__(64) void rowsq_kernel(
    const float* __restrict__ X, float* __restrict__ out,
    float* __restrict__ loss_slot)
{
    const int r = blockIdx.x;
    const float4 v = reinterpret_cast<const float4*>(X + (size_t)r * LAT_)[threadIdx.x];
    double s = (double)v.x * v.x + (double)v.y * v.y + (double)v.z * v.z + (double)v.w * v.w;
#pragma unroll
    for (int off = 32; off; off >>= 1) s += __shfl_down(s, off, 64);
    if (threadIdx.x == 0) {
        out[r] = (float)s;
        if (loss_slot != nullptr && r == 0) *loss_slot = 0.0f;
    }
}

// ---------------------------------------------------------------------------
// Finalize: reduce 8 partials -> index (float), gather z_q (bf16), loss atomics
// ---------------------------------------------------------------------------
__global__ __launch_bounds__(64) void vq_finalize(
    const float* __restrict__ pval, const int* __restrict__ pidx,
    const float* __restrict__ Z, const float* __restrict__ E,
    unsigned short* __restrict__ zqb, float* __restrict__ out_idx,
    float* __restrict__ loss_slot)
{
    const int row = blockIdx.x;
    __shared__ int sidx;
    if (threadIdx.x == 0) {
        float bv = pval[row * 8]; int bi = pidx[row * 8];
#pragma unroll
        for (int s = 1; s < 8; ++s) {
            const float v = pval[row * 8 + s]; const int ix = pidx[row * 8 + s];
            if (v < bv || (v == bv && ix < bi)) { bv = v; bi = ix; }
        }
        sidx = bi;
        out_idx[row] = (float)bi;
    }
    __syncthreads();
    const int idx = sidx;
    const float4 e = reinterpret_cast<const float4*>(E + (size_t)idx * LAT_)[threadIdx.x];
    const float4 z = reinterpret_cast<const float4*>(Z + (size_t)row * LAT_)[threadIdx.x];
    ushort4 q; q.x = f2bf(e.x); q.y = f2bf(e.y); q.z = f2bf(e.z); q.w = f2bf(e.w);
    reinterpret_cast<ushort4*>(zqb + (size_t)row * LAT_)[threadIdx.x] = q;
    const float dx = z.x - e.x, dy = z.y - e.y, dz = z.z - e.z, dw = z.w - e.w;
    float s = dx * dx + dy * dy + dz * dz + dw * dw;
#pragma unroll
    for (int off = 32; off; off >>= 1) s += __shfl_down(s, off, 64);
    if (threadIdx.x == 0)
        atomicAdd(loss_slot, s * (1.25f / ((float)B_ * (float)LAT_)));
}

// ---------------------------------------------------------------------------
extern "C" void kernel_launch(void* const* d_in, const int* in_sizes, int n_in,
                              void* d_out, int out_size, void* d_ws, size_t ws_size,
                              hipStream_t stream)
{
    const float* x   = (const float*)d_in[0];
    const float* W1  = (const float*)d_in[1];
    const float* b1  = (const float*)d_in[2];
    const float* W2  = (const float*)d_in[3];
    const float* b2  = (const float*)d_in[4];
    const float* W3  = (const float*)d_in[5];
    const float* b3  = (const float*)d_in[6];
    const float* emb = (const float*)d_in[7];
    const float* D1  = (const float*)d_in[8];
    const float* d1  = (const float*)d_in[9];
    const float* D2  = (const float*)d_in[10];
    const float* d2  = (const float*)d_in[11];
    const float* D3  = (const float*)d_in[12];
    const float* d3  = (const float*)d_in[13];
    float* out = (float*)d_out;

    // Workspace map (peak 153 MB < proven 156 MB). 1 MB = 1<<20. Overlays:
    //  [  0, 32M)  h1hi  -> zehi [0,4M), zelo [4,8M) after enc3 -> g1b after vq
    //  [ 32, 64M)  h1lo  -> zqb [32,36M) after enc2 -> g2b after dec1
    //  [ 64, 96M)  xhi[64,80) xlo[80,96) -> h2hi (enc2) -> wt1/wt2/wt3 after enc3
    //  [ 96,128M)  h2lo
    //  [128,136M)  ze fp32
    //  [136,152M)  enc weight splits W1T/W2T/W3T; ehi[144,146) elo[146,148) after enc2
    //  [152,153M)  esq, zsq, pval, pidx
    char* ws = (char*)d_ws;
    const size_t MB = 1u << 20;
    unsigned short* h1hi = (unsigned short*)(ws);
    unsigned short* h1lo = (unsigned short*)(ws + 32 * MB);
    unsigned short* zehi = (unsigned short*)(ws);           // after enc3
    unsigned short* zelo = (unsigned short*)(ws + 4 * MB);  // after enc3
    unsigned short* g1b  = (unsigned short*)(ws);           // after vq
    unsigned short* zqb  = (unsigned short*)(ws + 32 * MB); // after enc2
    unsigned short* g2b  = (unsigned short*)(ws + 32 * MB); // after dec1
    unsigned short* xhi  = (unsigned short*)(ws + 64 * MB);
    unsigned short* xlo  = (unsigned short*)(ws + 80 * MB);
    unsigned short* h2hi = (unsigned short*)(ws + 64 * MB); // after enc1
    unsigned short* h2lo = (unsigned short*)(ws + 96 * MB);
    unsigned short* wt1  = (unsigned short*)(ws + 64 * MB); // after enc3
    unsigned short* wt2  = (unsigned short*)(ws + 65 * MB);
    unsigned short* wt3  = (unsigned short*)(ws + 73 * MB);
    float* ze = (float*)(ws + 128 * MB);
    unsigned short* w1thi = (unsigned short*)(ws + 136 * MB);
    unsigned short* w1tlo = (unsigned short*)(ws + 140 * MB);
    unsigned short* w2thi = (unsigned short*)(ws + 136 * MB); // after enc1
    unsigned short* w2tlo = (unsigned short*)(ws + 144 * MB);
    unsigned short* w3thi = (unsigned short*)(ws + 136 * MB); // after enc2
    unsigned short* w3tlo = (unsigned short*)(ws + 137 * MB);
    unsigned short* ehi   = (unsigned short*)(ws + 144 * MB); // after enc2 (w2tlo dead)
    unsigned short* elo   = (unsigned short*)(ws + 146 * MB);
    float* esq  = (float*)(ws + 152 * MB);
    float* zsq  = (float*)(ws + 152 * MB + 64 * 1024);
    float* pval = (float*)(ws + 152 * MB + 128 * 1024);
    int*   pidx = (int*)  (ws + 152 * MB + 384 * 1024);

    float* loss_slot = out + (size_t)B_ * DIN_;     // d_out[8388608]
    float* out_idx   = loss_slot + 1;               // d_out[8388609..]

    // codebook prep (esq kernel also zeroes loss slot)
    rowsq_kernel<<<KC_, 64, 0, stream>>>(emb, esq, loss_slot);

    // input + first-layer weight splits
    split_scaled_f16x2<<<(B_ * DIN_ / 4 + 255) / 256, 256, 0, stream>>>(
        x, xhi, xlo, B_ * DIN_ / 4, 1.0f);
    wsplit_transpose<<<dim3(DIN_ / 32, HID_ / 32), dim3(32, 8), 0, stream>>>(W1, w1thi, w1tlo, DIN_, HID_);

    // enc1: x -> h1 (split output)
    gemm_split_f16<1, 1><<<dim3(HID_ / 64, B_ / 128), 256, 0, stream>>>(
        xhi, xlo, w1thi, w1tlo, b1, h1hi, h1lo, nullptr, B_, HID_, DIN_);

    // W2 split (overlays W1T; after enc1)
    wsplit_transpose<<<dim3(HID_ / 32, HID_ / 32), dim3(32, 8), 0, stream>>>(W2, w2thi, w2tlo, HID_, HID_);

    // enc2: h1 -> h2 (xsplit dead, h2hi overlays it)
    gemm_split_f16<1, 1><<<dim3(HID_ / 64, B_ / 128), 256, 0, stream>>>(
        h1hi, h1lo, w2thi, w2tlo, b2, h2hi, h2lo, nullptr, B_, HID_, HID_);

    // codebook split (x2^16, over dead w2tlo region) + W3 split (after enc2)
    split_scaled_f16x2<<<(KC_ * LAT_ / 4 + 255) / 256, 256, 0, stream>>>(
        emb, ehi, elo, KC_ * LAT_ / 4, 65536.0f);
    wsplit_transpose<<<dim3(HID_ / 32, LAT_ / 32), dim3(32, 8), 0, stream>>>(W3, w3thi, w3tlo, HID_, LAT_);

    // enc3: h2 -> ze fp32 + (zehi, zelo) fused split, no gelu
    gemm_split_f16<0, 2><<<dim3(LAT_ / 64, B_ / 128), 256, 0, stream>>>(
        h2hi, h2lo, w3thi, w3tlo, b3, zehi, zelo, ze, B_, LAT_, HID_);

    // z row norms
    rowsq_kernel<<<B_, 64, 0, stream>>>(ze, zsq, nullptr);

    // decoder weight prep (h2 dead after enc3; wt* overlay it)
    cast_transpose_w<<<dim3(LAT_ / 32, HID_ / 32), dim3(32, 8), 0, stream>>>(D1, wt1, LAT_, HID_);
    cast_transpose_w<<<dim3(HID_ / 32, HID_ / 32), dim3(32, 8), 0, stream>>>(D2, wt2, HID_, HID_);
    cast_transpose_w<<<dim3(HID_ / 32, DIN_ / 32), dim3(32, 8), 0, stream>>>(D3, wt3, HID_, DIN_);

    // VQ — MFMA split distances, numpy-fp32-mimicking scores, first-index ties
    vq_argmin_mfma<<<dim3(B_ / 128, 8), 256, 0, stream>>>(
        zehi, zelo, ehi, elo, esq, zsq, pval, pidx);
    vq_finalize<<<B_, 64, 0, stream>>>(pval, pidx, ze, emb, zqb, out_idx, loss_slot);

    // decoder — bf16 MFMA (unchanged numerics)
    gemm_mfma_bf16<1><<<dim3(B_ / 128, HID_ / 128), 256, 0, stream>>>(zqb, wt1, d1, (void*)g1b, B_, HID_, LAT_);
    gemm_mfma_bf16<1><<<dim3(B_ / 128, HID_ / 128), 256, 0, stream>>>(g1b, wt2, d2, (void*)g2b, B_, HID_, HID_);
    gemm_mfma_bf16<0><<<dim3(B_ / 128, DIN_ / 128), 256, 0, stream>>>(g2b, wt3, d3, (void*)out, B_, DIN_, HID_);
}

// Round 4
// 1023.598 us; speedup vs baseline: 3.2796x; 1.0717x over previous
//
#include <hip/hip_runtime.h>
#include <math.h>

// Problem constants
#define B_    8192
#define DIN_  1024
#define HID_  2048
#define LAT_  256
#define KC_   4096   // codebook size

using bfrag8 = __attribute__((ext_vector_type(8))) short;   // 8 bf16 (4 VGPR)
using short8 = __attribute__((ext_vector_type(8))) short;
using half8  = __attribute__((ext_vector_type(8))) _Float16;
using facc4  = __attribute__((ext_vector_type(4))) float;   // MFMA C/D frag

__device__ __forceinline__ unsigned short f2bf(float f) {
    union { float f; unsigned int u; } c; c.f = f;
    unsigned int u = c.u;
    return (unsigned short)((u + 0x7FFFu + ((u >> 16) & 1u)) >> 16);   // RNE
}

__device__ __forceinline__ unsigned short f2h_bits(float f) {
    union { _Float16 h; unsigned short u; } c; c.h = (_Float16)f;
    return c.u;
}

// Async global->LDS, 16B per lane. LDS dest is wave-uniform base + lane*16.
__device__ __forceinline__ void gload16(const unsigned short* g, unsigned short* l) {
    __builtin_amdgcn_global_load_lds(
        (const __attribute__((address_space(1))) void*)(g),
        (__attribute__((address_space(3))) void*)(l), 16, 0, 0);
}

// ---------------------------------------------------------------------------
// Encoder GEMM via fp16-split MFMA (Ozaki-style, 2 components, 3 classes).
// Staging via global_load_lds: LDS dest linear in lane order; global source
// granule pre-swizzled g^(row&7) so LDS contents are BYTE-IDENTICAL to the
// verified XOR layout (read side unchanged -> bit-identical results).
// OUT_SPLIT: 0 = f32 only, 1 = f16 split only, 2 = f32 + f16 split.
// ---------------------------------------------------------------------------
template <int GELU, int OUT_SPLIT>
__global__ __launch_bounds__(256, 3) void gemm_split_f16(
    const unsigned short* __restrict__ Ahi, const unsigned short* __restrict__ Alo,
    const unsigned short* __restrict__ WThi, const unsigned short* __restrict__ WTlo,
    const float* __restrict__ bias,
    unsigned short* __restrict__ Chi, unsigned short* __restrict__ Clo,
    float* __restrict__ Cf32,
    int M, int N, int K)
{
    __shared__ __align__(16) unsigned short AsH[128 * 64];   // 16 KB
    __shared__ __align__(16) unsigned short AsL[128 * 64];   // 16 KB
    __shared__ __align__(16) unsigned short WsH[64 * 64];    // 8 KB
    __shared__ __align__(16) unsigned short WsL[64 * 64];    // 8 KB

    const int tid  = threadIdx.x;
    const int wave = tid >> 6;
    const int lane = tid & 63;
    const int wm   = wave & 1;        // wave row (2x2 wave grid)
    const int wn   = wave >> 1;       // wave col
    const int quad = lane >> 4;
    const int ln   = lane & 15;
    const int n0 = blockIdx.x * 64;   // x = n-tile: consecutive blocks share A tile (L2)
    const int m0 = blockIdx.y * 128;

    const facc4 fz4 = {0.0f, 0.0f, 0.0f, 0.0f};
    facc4 accA[4][2] = {};    // hi*hi, scale 64, reset every 256 k
    facc4 accB[4][2] = {};    // hi*lo + lo*hi, scale 64*4096, full-K chain
    facc4 master[4][2] = {};  // blocked sum of accA

    for (int k0 = 0; k0 < K; k0 += 64) {
        // stage A tiles 128x64 (hi+lo): dest linear, source granule-swizzled
#pragma unroll
        for (int i = 0; i < 4; ++i) {
            const int idx = i * 256 + tid;
            const int row = idx >> 3;
            const int gs  = (idx & 7) ^ (row & 7);
            const int wb  = i * 256 + (tid & 192);     // wave-uniform granule base
            const size_t src = (size_t)(m0 + row) * K + k0 + gs * 8;
            gload16(&Ahi[src], &AsH[wb * 8]);
            gload16(&Alo[src], &AsL[wb * 8]);
        }
        // stage W tiles 64x64 (hi+lo)
#pragma unroll
        for (int i = 0; i < 2; ++i) {
            const int idx = i * 256 + tid;
            const int row = idx >> 3;
            const int gs  = (idx & 7) ^ (row & 7);
            const int wb  = i * 256 + (tid & 192);
            const size_t src = (size_t)(n0 + row) * K + k0 + gs * 8;
            gload16(&WThi[src], &WsH[wb * 8]);
            gload16(&WTlo[src], &WsL[wb * 8]);
        }
        __syncthreads();
#pragma unroll
        for (int ks = 0; ks < 64; ks += 32) {
            const int gq = (ks >> 3) + quad;      // source granule for this chunk
            half8 aH[4], aL[4], bH[2], bL[2];
#pragma unroll
            for (int f = 0; f < 4; ++f) {
                const int row = wm * 64 + f * 16 + ln;
                const int off = row * 64 + ((gq ^ (ln & 7)) << 3);
                aH[f] = *reinterpret_cast<const half8*>(&AsH[off]);
                aL[f] = *reinterpret_cast<const half8*>(&AsL[off]);
            }
#pragma unroll
            for (int f = 0; f < 2; ++f) {
                const int row = wn * 32 + f * 16 + ln;
                const int off = row * 64 + ((gq ^ (ln & 7)) << 3);
                bH[f] = *reinterpret_cast<const half8*>(&WsH[off]);
                bL[f] = *reinterpret_cast<const half8*>(&WsL[off]);
            }
#pragma unroll
            for (int fm = 0; fm < 4; ++fm)
#pragma unroll
                for (int fn = 0; fn < 2; ++fn)
                    accA[fm][fn] = __builtin_amdgcn_mfma_f32_16x16x32_f16(
                        aH[fm], bH[fn], accA[fm][fn], 0, 0, 0);
#pragma unroll
            for (int fm = 0; fm < 4; ++fm)
#pragma unroll
                for (int fn = 0; fn < 2; ++fn)
                    accB[fm][fn] = __builtin_amdgcn_mfma_f32_16x16x32_f16(
                        aH[fm], bL[fn], accB[fm][fn], 0, 0, 0);
#pragma unroll
            for (int fm = 0; fm < 4; ++fm)
#pragma unroll
                for (int fn = 0; fn < 2; ++fn)
                    accB[fm][fn] = __builtin_amdgcn_mfma_f32_16x16x32_f16(
                        aL[fm], bH[fn], accB[fm][fn], 0, 0, 0);
        }
        __syncthreads();
        if ((k0 & 192) == 192) {            // end of each 256-k block: promote
#pragma unroll
            for (int fm = 0; fm < 4; ++fm)
#pragma unroll
                for (int fn = 0; fn < 2; ++fn) {
                    master[fm][fn] += accA[fm][fn];
                    accA[fm][fn] = fz4;
                }
        }
    }

    const double SC_HI = 0.015625;               // 1/64
    const double SC_LO = 3.814697265625e-06;     // 1/(64*4096)
#pragma unroll
    for (int fn = 0; fn < 2; ++fn) {
        const int col = n0 + wn * 32 + fn * 16 + ln;
        const double bb = (double)bias[col];
#pragma unroll
        for (int fm = 0; fm < 4; ++fm) {
            const int rbase = m0 + wm * 64 + fm * 16 + quad * 4;
#pragma unroll
            for (int r = 0; r < 4; ++r) {
                double v = (double)master[fm][fn][r] * SC_HI
                         + (double)accB[fm][fn][r] * SC_LO + bb;
                if (GELU) v = 0.5 * v * (1.0 + erf(v * 0.70710678118654752440));
                const float hf = (float)v;
                if (OUT_SPLIT == 1 || OUT_SPLIT == 2) {
                    const _Float16 hi = (_Float16)hf;
                    const float lo = (hf - (float)hi) * 4096.0f;
                    union { _Float16 h; unsigned short u; } c1, c2;
                    c1.h = hi; c2.h = (_Float16)lo;
                    Chi[(size_t)(rbase + r) * N + col] = c1.u;
                    Clo[(size_t)(rbase + r) * N + col] = c2.u;
                }
                if (OUT_SPLIT == 0 || OUT_SPLIT == 2) {
                    Cf32[(size_t)(rbase + r) * N + col] = hf;
                }
            }
        }
    }
}

// ---------------------------------------------------------------------------
// Split fp32 -> (hi, lo*4096) fp16 pair, with pre-scale: v' = v*scale.
// scale must be a power of two (exact). Used for x (1.0).
// ---------------------------------------------------------------------------
__global__ __launch_bounds__(256) void split_scaled_f16x2(
    const float* __restrict__ X, unsigned short* __restrict__ Xhi,
    unsigned short* __restrict__ Xlo, int n4, float scale)
{
    const int i = blockIdx.x * 256 + threadIdx.x;
    if (i >= n4) return;
    const float4 v = reinterpret_cast<const float4*>(X)[i];
    ushort4 h, l;
    {
        const float s = v.x * scale;
        _Float16 a = (_Float16)s; h.x = f2h_bits((float)a); l.x = f2h_bits((s - (float)a) * 4096.0f);
    }
    {
        const float s = v.y * scale;
        _Float16 a = (_Float16)s; h.y = f2h_bits((float)a); l.y = f2h_bits((s - (float)a) * 4096.0f);
    }
    {
        const float s = v.z * scale;
        _Float16 a = (_Float16)s; h.z = f2h_bits((float)a); l.z = f2h_bits((s - (float)a) * 4096.0f);
    }
    {
        const float s = v.w * scale;
        _Float16 a = (_Float16)s; h.w = f2h_bits((float)a); l.w = f2h_bits((s - (float)a) * 4096.0f);
    }
    reinterpret_cast<ushort4*>(Xhi)[i] = h;
    reinterpret_cast<ushort4*>(Xlo)[i] = l;
}

// ---------------------------------------------------------------------------
// Fused codebook prep: one pass over embed [4096,256].
//   esq[r] = fp32( fp64 shfl-reduce sum of row^2 )   (bit-identical to rowsq)
//   ehi/elo = f16 split of embed * 2^16              (bit-identical to split)
//   zeroes loss_slot at r==0.
// ---------------------------------------------------------------------------
__global__ __launch_bounds__(64) void emb_prep(
    const float* __restrict__ E, float* __restrict__ esq,
    unsigned short* __restrict__ Ehi, unsigned short* __restrict__ Elo,
    float* __restrict__ loss_slot)
{
    const int r = blockIdx.x;
    const float4 v = reinterpret_cast<const float4*>(E + (size_t)r * LAT_)[threadIdx.x];
    // split (scale 2^16, exact)
    ushort4 h, l;
    {
        const float s = v.x * 65536.0f;
        _Float16 a = (_Float16)s; h.x = f2h_bits((float)a); l.x = f2h_bits((s - (float)a) * 4096.0f);
    }
    {
        const float s = v.y * 65536.0f;
        _Float16 a = (_Float16)s; h.y = f2h_bits((float)a); l.y = f2h_bits((s - (float)a) * 4096.0f);
    }
    {
        const float s = v.z * 65536.0f;
        _Float16 a = (_Float16)s; h.z = f2h_bits((float)a); l.z = f2h_bits((s - (float)a) * 4096.0f);
    }
    {
        const float s = v.w * 65536.0f;
        _Float16 a = (_Float16)s; h.w = f2h_bits((float)a); l.w = f2h_bits((s - (float)a) * 4096.0f);
    }
    reinterpret_cast<ushort4*>(Ehi + (size_t)r * LAT_)[threadIdx.x] = h;
    reinterpret_cast<ushort4*>(Elo + (size_t)r * LAT_)[threadIdx.x] = l;
    // rowsq (identical math/order to rowsq_kernel)
    double s = (double)v.x * v.x + (double)v.y * v.y + (double)v.z * v.z + (double)v.w * v.w;
#pragma unroll
    for (int off = 32; off; off >>= 1) s += __shfl_down(s, off, 64);
    if (threadIdx.x == 0) {
        esq[r] = (float)s;
        if (r == 0) *loss_slot = 0.0f;
    }
}

// ---------------------------------------------------------------------------
// Weight prep: W [K,N] fp32 -> WThi/WTlo [N,K] f16 of (W*64, residual*4096).
// ---------------------------------------------------------------------------
__global__ __launch_bounds__(256) void wsplit_transpose(
    const float* __restrict__ W, unsigned short* __restrict__ WThi,
    unsigned short* __restrict__ WTlo, int K, int N)
{
    __shared__ float t[32][33];
    const int k0 = blockIdx.x * 32;
    const int n0 = blockIdx.y * 32;
    const int x = threadIdx.x;
    const int y = threadIdx.y;
#pragma unroll
    for (int i = 0; i < 4; ++i)
        t[y + i * 8][x] = W[(size_t)(k0 + y + i * 8) * N + n0 + x];
    __syncthreads();
#pragma unroll
    for (int i = 0; i < 4; ++i) {
        const float w = t[x][y + i * 8] * 64.0f;
        const _Float16 hi = (_Float16)w;
        const float lo = (w - (float)hi) * 4096.0f;
        WThi[(size_t)(n0 + y + i * 8) * K + k0 + x] = f2h_bits((float)hi);
        WTlo[(size_t)(n0 + y + i * 8) * K + k0 + x] = f2h_bits(lo);
    }
}

// ---------------------------------------------------------------------------
// VQ distance + argmin via fp16-split MFMA.
//   t2m = (accA*2^-15f) + (accB*2^-27f): both scalings exact (power-2), the
//   f32 sum rounds the same exact value the old f64 path rounded -> scores
//   BIT-IDENTICAL to the verified round-2/3 kernel.
//   Argmin deferred: per-lane running best over (nt, fn) — candidate n is
//   strictly ascending per lane, so strict < == first-index semantics; one
//   butterfly (index tie-break) at kernel end + LDS wn-merge. Removes the
//   per-tile shuffle + fp64 epilogue that dominated this kernel.
// ---------------------------------------------------------------------------
__global__ __launch_bounds__(256, 2) void vq_argmin_mfma(
    const unsigned short* __restrict__ Zhi, const unsigned short* __restrict__ Zlo,
    const unsigned short* __restrict__ Ehi, const unsigned short* __restrict__ Elo,
    const float* __restrict__ esq, const float* __restrict__ zsq,
    float* __restrict__ pval, int* __restrict__ pidx)
{
    __shared__ __align__(16) unsigned short ZsH[128 * 64];   // 16 KB
    __shared__ __align__(16) unsigned short ZsL[128 * 64];   // 16 KB
    __shared__ __align__(16) unsigned short EsH[64 * 64];    // 8 KB
    __shared__ __align__(16) unsigned short EsL[64 * 64];    // 8 KB
    __shared__ float rbv[128][2];
    __shared__ int   rbi[128][2];

    const int tid  = threadIdx.x;
    const int wave = tid >> 6;
    const int lane = tid & 63;
    const int wm   = wave & 1;        // wave row (2x2 wave grid)
    const int wn   = wave >> 1;       // wave col
    const int quad = lane >> 4;
    const int ln   = lane & 15;
    const int m0    = blockIdx.x * 128;
    const int split = blockIdx.y;

    // hoist z row norms (per-lane constants)
    float zsqv[4][4];
#pragma unroll
    for (int fm = 0; fm < 4; ++fm) {
        const float4 q = *reinterpret_cast<const float4*>(
            &zsq[m0 + wm * 64 + fm * 16 + quad * 4]);
        zsqv[fm][0] = q.x; zsqv[fm][1] = q.y; zsqv[fm][2] = q.z; zsqv[fm][3] = q.w;
    }

    float bestv[4][4];
    int   besti[4][4];
#pragma unroll
    for (int a = 0; a < 4; ++a)
#pragma unroll
        for (int b = 0; b < 4; ++b) { bestv[a][b] = 3.4e38f; besti[a][b] = 0; }

    for (int nt = 0; nt < 8; ++nt) {
        const int n0 = split * 512 + nt * 64;
        facc4 accA[4][2] = {};
        facc4 accB[4][2] = {};
        for (int k0 = 0; k0 < 256; k0 += 64) {
            __syncthreads();   // previous phase's LDS readers done
            // stage Z tile 128x64 (hi+lo)
#pragma unroll
            for (int i = 0; i < 4; ++i) {
                const int idx = i * 256 + tid;
                const int row = idx >> 3;
                const int gs  = (idx & 7) ^ (row & 7);
                const int wb  = i * 256 + (tid & 192);
                const size_t src = (size_t)(m0 + row) * LAT_ + k0 + gs * 8;
                gload16(&Zhi[src], &ZsH[wb * 8]);
                gload16(&Zlo[src], &ZsL[wb * 8]);
            }
            // stage E tile 64x64 (hi+lo)
#pragma unroll
            for (int i = 0; i < 2; ++i) {
                const int idx = i * 256 + tid;
                const int row = idx >> 3;
                const int gs  = (idx & 7) ^ (row & 7);
                const int wb  = i * 256 + (tid & 192);
                const size_t src = (size_t)(n0 + row) * LAT_ + k0 + gs * 8;
                gload16(&Ehi[src], &EsH[wb * 8]);
                gload16(&Elo[src], &EsL[wb * 8]);
            }
            __syncthreads();
#pragma unroll
            for (int ks = 0; ks < 64; ks += 32) {
                const int gq = (ks >> 3) + quad;
                half8 aH[4], aL[4], bH[2], bL[2];
#pragma unroll
                for (int f = 0; f < 4; ++f) {
                    const int row = wm * 64 + f * 16 + ln;
                    const int off = row * 64 + ((gq ^ (ln & 7)) << 3);
                    aH[f] = *reinterpret_cast<const half8*>(&ZsH[off]);
                    aL[f] = *reinterpret_cast<const half8*>(&ZsL[off]);
                }
#pragma unroll
                for (int f = 0; f < 2; ++f) {
                    const int row = wn * 32 + f * 16 + ln;
                    const int off = row * 64 + ((gq ^ (ln & 7)) << 3);
                    bH[f] = *reinterpret_cast<const half8*>(&EsH[off]);
                    bL[f] = *reinterpret_cast<const half8*>(&EsL[off]);
                }
#pragma unroll
                for (int fm = 0; fm < 4; ++fm)
#pragma unroll
                    for (int fn = 0; fn < 2; ++fn)
                        accA[fm][fn] = __builtin_amdgcn_mfma_f32_16x16x32_f16(
                            aH[fm], bH[fn], accA[fm][fn], 0, 0, 0);
#pragma unroll
                for (int fm = 0; fm < 4; ++fm)
#pragma unroll
                    for (int fn = 0; fn < 2; ++fn)
                        accB[fm][fn] = __builtin_amdgcn_mfma_f32_16x16x32_f16(
                            aH[fm], bL[fn], accB[fm][fn], 0, 0, 0);
#pragma unroll
                for (int fm = 0; fm < 4; ++fm)
#pragma unroll
                    for (int fn = 0; fn < 2; ++fn)
                        accB[fm][fn] = __builtin_amdgcn_mfma_f32_16x16x32_f16(
                            aL[fm], bH[fn], accB[fm][fn], 0, 0, 0);
            }
        }
        // per-lane score + running best (strict <: candidates ascend in n)
#pragma unroll
        for (int fm = 0; fm < 4; ++fm)
#pragma unroll
            for (int fn = 0; fn < 2; ++fn) {
                const int n = n0 + wn * 32 + fn * 16 + ln;
                const float es = esq[n];
#pragma unroll
                for (int r = 0; r < 4; ++r) {
                    const float pa = accA[fm][fn][r] * 0x1p-15f;   // exact
                    const float pb = accB[fm][fn][r] * 0x1p-27f;   // exact
                    const float t2m = pa + pb;        // == old f64->f32 rounding
                    const float sc = (zsqv[fm][r] + es) - t2m;
                    if (sc < bestv[fm][r]) { bestv[fm][r] = sc; besti[fm][r] = n; }
                }
            }
    }

    // final butterfly across the 16 column slots (index tie-break)
#pragma unroll
    for (int fm = 0; fm < 4; ++fm)
#pragma unroll
        for (int r = 0; r < 4; ++r) {
            float v0 = bestv[fm][r]; int i0 = besti[fm][r];
#pragma unroll
            for (int mask = 1; mask < 16; mask <<= 1) {
                const float v2 = __shfl_xor(v0, mask, 64);
                const int   i2 = __shfl_xor(i0, mask, 64);
                if (v2 < v0 || (v2 == v0 && i2 < i0)) { v0 = v2; i0 = i2; }
            }
            bestv[fm][r] = v0; besti[fm][r] = i0;
        }

    if (ln == 0) {
#pragma unroll
        for (int fm = 0; fm < 4; ++fm)
#pragma unroll
            for (int r = 0; r < 4; ++r) {
                const int rl = wm * 64 + fm * 16 + quad * 4 + r;
                rbv[rl][wn] = bestv[fm][r];
                rbi[rl][wn] = besti[fm][r];
            }
    }
    __syncthreads();
    if (tid < 128) {
        float bv = rbv[tid][0]; int bi = rbi[tid][0];
        const float v = rbv[tid][1]; const int ix = rbi[tid][1];
        if (v < bv || (v == bv && ix < bi)) { bv = v; bi = ix; }
        pval[(size_t)(m0 + tid) * 8 + split] = bv;
        pidx[(m0 + tid) * 8 + split] = bi;
    }
}

// ---------------------------------------------------------------------------
// Decoder GEMM: bf16 MFMA 16x16x32 (staging via global_load_lds; LDS layout
// and numerics identical to verified version)
// ---------------------------------------------------------------------------
template <int OUT_BF16>
__global__ __launch_bounds__(256) void gemm_mfma_bf16(
    const unsigned short* __restrict__ A,
    const unsigned short* __restrict__ WT,
    const float* __restrict__ bias,
    void* __restrict__ Cout,
    int M, int N, int K)
{
    __shared__ __align__(16) unsigned short As[128 * 64];   // [m][k], 16 KB
    __shared__ __align__(16) unsigned short Bs[128 * 64];   // [n][k], 16 KB

    const int tid  = threadIdx.x;
    const int wave = tid >> 6;
    const int lane = tid & 63;
    const int wm   = wave & 1;
    const int wn   = wave >> 1;
    const int quad = lane >> 4;
    const int ln   = lane & 15;
    const int m0 = blockIdx.x * 128;
    const int n0 = blockIdx.y * 128;

    facc4 acc[4][4] = {};

    for (int k0 = 0; k0 < K; k0 += 64) {
#pragma unroll
        for (int i = 0; i < 4; ++i) {
            const int idx = i * 256 + tid;
            const int row = idx >> 3;
            const int c8  = (idx & 7) * 8;
            const int wb  = i * 256 + (tid & 192);
            gload16(&A[(size_t)(m0 + row) * K + k0 + c8], &As[wb * 8]);
            gload16(&WT[(size_t)(n0 + row) * K + k0 + c8], &Bs[wb * 8]);
        }
        __syncthreads();
#pragma unroll
        for (int ks = 0; ks < 64; ks += 32) {
            bfrag8 am[4], bn[4];
#pragma unroll
            for (int f = 0; f < 4; ++f) {
                am[f] = *reinterpret_cast<const bfrag8*>(
                    &As[(wm * 64 + f * 16 + ln) * 64 + ks + quad * 8]);
                bn[f] = *reinterpret_cast<const bfrag8*>(
                    &Bs[(wn * 64 + f * 16 + ln) * 64 + ks + quad * 8]);
            }
#pragma unroll
            for (int fm = 0; fm < 4; ++fm)
#pragma unroll
                for (int fn = 0; fn < 4; ++fn)
                    acc[fm][fn] = __builtin_amdgcn_mfma_f32_16x16x32_bf16(
                        am[fm], bn[fn], acc[fm][fn], 0, 0, 0);
        }
        __syncthreads();
    }

#pragma unroll
    for (int fn = 0; fn < 4; ++fn) {
        const int col = n0 + wn * 64 + fn * 16 + ln;
        const float bf = bias[col];
#pragma unroll
        for (int fm = 0; fm < 4; ++fm) {
            const int rbase = m0 + wm * 64 + fm * 16 + quad * 4;
#pragma unroll
            for (int r = 0; r < 4; ++r) {
                float v = acc[fm][fn][r] + bf;
                if (OUT_BF16) {
                    v = 0.5f * v * (1.0f + erff(v * 0.70710678118654752440f));
                    ((unsigned short*)Cout)[(size_t)(rbase + r) * N + col] = f2bf(v);
                } else {
                    ((float*)Cout)[(size_t)(rbase + r) * N + col] = v;
                }
            }
        }
    }
}

// ---------------------------------------------------------------------------
// Cast+transpose weights: W [K,N] fp32 -> WT [N,K] bf16 (decoder, unchanged)
// ---------------------------------------------------------------------------
__global__ __launch_bounds__(256) void cast_transpose_w(
    const float* __restrict__ W, unsigned short* __restrict__ WT, int K, int N)
{
    __shared__ float t[32][33];
    const int k0 = blockIdx.x * 32;
    const int n0 = blockIdx.y * 32;
    const int x = threadIdx.x;
    const int y = threadIdx.y;
#pragma unroll
    for (int i = 0; i < 4; ++i)
        t[y + i * 8][x] = W[(size_t)(k0 + y + i * 8) * N + n0 + x];
    __syncthreads();
#pragma unroll
    for (int i = 0; i < 4; ++i)
        WT[(size_t)(n0 + y + i * 8) * K + k0 + x] = f2bf(t[x][y + i * 8]);
}

// ---------------------------------------------------------------------------
// rowsq[r] = fp32( fp64 sum of X[r,:].^2 ), rows of width LAT_=256.
// ---------------------------------------------------------------------------
__global__ __launch_bounds__(64) void rowsq_kernel(
    const float* __restrict__ X, float* __restrict__ out,
    float* __restrict__ loss_slot)
{
    const int r = blockIdx.x;
    const float4 v = reinterpret_cast<const float4*>(X + (size_t)r * LAT_)[threadIdx.x];
    double s = (double)v.x * v.x + (double)v.y * v.y + (double)v.z * v.z + (double)v.w * v.w;
#pragma unroll
    for (int off = 32; off; off >>= 1) s += __shfl_down(s, off, 64);
    if (threadIdx.x == 0) {
        out[r] = (float)s;
        if (loss_slot != nullptr && r == 0) *loss_slot = 0.0f;
    }
}

// ---------------------------------------------------------------------------
// Finalize: reduce 8 partials -> index (float), gather z_q (bf16), loss atomics
// ---------------------------------------------------------------------------
__global__ __launch_bounds__(64) void vq_finalize(
    const float* __restrict__ pval, const int* __restrict__ pidx,
    const float* __restrict__ Z, const float* __restrict__ E,
    unsigned short* __restrict__ zqb, float* __restrict__ out_idx,
    float* __restrict__ loss_slot)
{
    const int row = blockIdx.x;
    __shared__ int sidx;
    if (threadIdx.x == 0) {
        float bv = pval[row * 8]; int bi = pidx[row * 8];
#pragma unroll
        for (int s = 1; s < 8; ++s) {
            const float v = pval[row * 8 + s]; const int ix = pidx[row * 8 + s];
            if (v < bv || (v == bv && ix < bi)) { bv = v; bi = ix; }
        }
        sidx = bi;
        out_idx[row] = (float)bi;
    }
    __syncthreads();
    const int idx = sidx;
    const float4 e = reinterpret_cast<const float4*>(E + (size_t)idx * LAT_)[threadIdx.x];
    const float4 z = reinterpret_cast<const float4*>(Z + (size_t)row * LAT_)[threadIdx.x];
    ushort4 q; q.x = f2bf(e.x); q.y = f2bf(e.y); q.z = f2bf(e.z); q.w = f2bf(e.w);
    reinterpret_cast<ushort4*>(zqb + (size_t)row * LAT_)[threadIdx.x] = q;
    const float dx = z.x - e.x, dy = z.y - e.y, dz = z.z - e.z, dw = z.w - e.w;
    float s = dx * dx + dy * dy + dz * dz + dw * dw;
#pragma unroll
    for (int off = 32; off; off >>= 1) s += __shfl_down(s, off, 64);
    if (threadIdx.x == 0)
        atomicAdd(loss_slot, s * (1.25f / ((float)B_ * (float)LAT_)));
}

// ---------------------------------------------------------------------------
extern "C" void kernel_launch(void* const* d_in, const int* in_sizes, int n_in,
                              void* d_out, int out_size, void* d_ws, size_t ws_size,
                              hipStream_t stream)
{
    const float* x   = (const float*)d_in[0];
    const float* W1  = (const float*)d_in[1];
    const float* b1  = (const float*)d_in[2];
    const float* W2  = (const float*)d_in[3];
    const float* b2  = (const float*)d_in[4];
    const float* W3  = (const float*)d_in[5];
    const float* b3  = (const float*)d_in[6];
    const float* emb = (const float*)d_in[7];
    const float* D1  = (const float*)d_in[8];
    const float* d1  = (const float*)d_in[9];
    const float* D2  = (const float*)d_in[10];
    const float* d2  = (const float*)d_in[11];
    const float* D3  = (const float*)d_in[12];
    const float* d3  = (const float*)d_in[13];
    float* out = (float*)d_out;

    // Workspace map (peak 153 MB < proven 156 MB). 1 MB = 1<<20. Overlays:
    //  [  0, 32M)  h1hi  -> zehi [0,4M), zelo [4,8M) after enc3 -> g1b after vq
    //  [ 32, 64M)  h1lo  -> zqb [32,36M) after enc2 -> g2b after dec1
    //  [ 64, 96M)  xhi[64,80) xlo[80,96) -> h2hi (enc2) -> wt1/wt2/wt3 after enc3
    //  [ 96,128M)  h2lo
    //  [128,136M)  ze fp32
    //  [136,152M)  enc weight splits W1T/W2T/W3T; ehi[144,146) elo[146,148) after enc2
    //  [152,153M)  esq, zsq, pval, pidx
    char* ws = (char*)d_ws;
    const size_t MB = 1u << 20;
    unsigned short* h1hi = (unsigned short*)(ws);
    unsigned short* h1lo = (unsigned short*)(ws + 32 * MB);
    unsigned short* zehi = (unsigned short*)(ws);           // after enc3
    unsigned short* zelo = (unsigned short*)(ws + 4 * MB);  // after enc3
    unsigned short* g1b  = (unsigned short*)(ws);           // after vq
    unsigned short* zqb  = (unsigned short*)(ws + 32 * MB); // after enc2
    unsigned short* g2b  = (unsigned short*)(ws + 32 * MB); // after dec1
    unsigned short* xhi  = (unsigned short*)(ws + 64 * MB);
    unsigned short* xlo  = (unsigned short*)(ws + 80 * MB);
    unsigned short* h2hi = (unsigned short*)(ws + 64 * MB); // after enc1
    unsigned short* h2lo = (unsigned short*)(ws + 96 * MB);
    unsigned short* wt1  = (unsigned short*)(ws + 64 * MB); // after enc3
    unsigned short* wt2  = (unsigned short*)(ws + 65 * MB);
    unsigned short* wt3  = (unsigned short*)(ws + 73 * MB);
    float* ze = (float*)(ws + 128 * MB);
    unsigned short* w1thi = (unsigned short*)(ws + 136 * MB);
    unsigned short* w1tlo = (unsigned short*)(ws + 140 * MB);
    unsigned short* w2thi = (unsigned short*)(ws + 136 * MB); // after enc1
    unsigned short* w2tlo = (unsigned short*)(ws + 144 * MB);
    unsigned short* w3thi = (unsigned short*)(ws + 136 * MB); // after enc2
    unsigned short* w3tlo = (unsigned short*)(ws + 137 * MB);
    unsigned short* ehi   = (unsigned short*)(ws + 144 * MB); // after enc2 (w2tlo dead)
    unsigned short* elo   = (unsigned short*)(ws + 146 * MB);
    float* esq  = (float*)(ws + 152 * MB);
    float* zsq  = (float*)(ws + 152 * MB + 64 * 1024);
    float* pval = (float*)(ws + 152 * MB + 128 * 1024);
    int*   pidx = (int*)  (ws + 152 * MB + 384 * 1024);

    float* loss_slot = out + (size_t)B_ * DIN_;     // d_out[8388608]
    float* out_idx   = loss_slot + 1;               // d_out[8388609..]

    // input + first-layer weight splits
    split_scaled_f16x2<<<(B_ * DIN_ / 4 + 255) / 256, 256, 0, stream>>>(
        x, xhi, xlo, B_ * DIN_ / 4, 1.0f);
    wsplit_transpose<<<dim3(DIN_ / 32, HID_ / 32), dim3(32, 8), 0, stream>>>(W1, w1thi, w1tlo, DIN_, HID_);

    // enc1: x -> h1 (split output)
    gemm_split_f16<1, 1><<<dim3(HID_ / 64, B_ / 128), 256, 0, stream>>>(
        xhi, xlo, w1thi, w1tlo, b1, h1hi, h1lo, nullptr, B_, HID_, DIN_);

    // W2 split (overlays W1T; after enc1)
    wsplit_transpose<<<dim3(HID_ / 32, HID_ / 32), dim3(32, 8), 0, stream>>>(W2, w2thi, w2tlo, HID_, HID_);

    // enc2: h1 -> h2 (xsplit dead, h2hi overlays it)
    gemm_split_f16<1, 1><<<dim3(HID_ / 64, B_ / 128), 256, 0, stream>>>(
        h1hi, h1lo, w2thi, w2tlo, b2, h2hi, h2lo, nullptr, B_, HID_, HID_);

    // fused codebook prep (esq + split x2^16 + loss zero; over dead w2tlo) +
    // W3 split (after enc2)
    emb_prep<<<KC_, 64, 0, stream>>>(emb, esq, ehi, elo, loss_slot);
    wsplit_transpose<<<dim3(HID_ / 32, LAT_ / 32), dim3(32, 8), 0, stream>>>(W3, w3thi, w3tlo, HID_, LAT_);

    // enc3: h2 -> ze fp32 + (zehi, zelo) fused split, no gelu
    gemm_split_f16<0, 2><<<dim3(LAT_ / 64, B_ / 128), 256, 0, stream>>>(
        h2hi, h2lo, w3thi, w3tlo, b3, zehi, zelo, ze, B_, LAT_, HID_);

    // z row norms
    rowsq_kernel<<<B_, 64, 0, stream>>>(ze, zsq, nullptr);

    // decoder weight prep (h2 dead after enc3; wt* overlay it)
    cast_transpose_w<<<dim3(LAT_ / 32, HID_ / 32), dim3(32, 8), 0, stream>>>(D1, wt1, LAT_, HID_);
    cast_transpose_w<<<dim3(HID_ / 32, HID_ / 32), dim3(32, 8), 0, stream>>>(D2, wt2, HID_, HID_);
    cast_transpose_w<<<dim3(HID_ / 32, DIN_ / 32), dim3(32, 8), 0, stream>>>(D3, wt3, HID_, DIN_);

    // VQ — MFMA split distances, numpy-fp32-mimicking scores, first-index ties
    vq_argmin_mfma<<<dim3(B_ / 128, 8), 256, 0, stream>>>(
        zehi, zelo, ehi, elo, esq, zsq, pval, pidx);
    vq_finalize<<<B_, 64, 0, stream>>>(pval, pidx, ze, emb, zqb, out_idx, loss_slot);

    // decoder — bf16 MFMA (unchanged numerics)
    gemm_mfma_bf16<1><<<dim3(B_ / 128, HID_ / 128), 256, 0, stream>>>(zqb, wt1, d1, (void*)g1b, B_, HID_, LAT_);
    gemm_mfma_bf16<1><<<dim3(B_ / 128, HID_ / 128), 256, 0, stream>>>(g1b, wt2, d2, (void*)g2b, B_, HID_, HID_);
    gemm_mfma_bf16<0><<<dim3(B_ / 128, DIN_ / 128), 256, 0, stream>>>(g2b, wt3, d3, (void*)out, B_, DIN_, HID_);
}